// Round 1
// baseline (10867.226 us; speedup 1.0000x reference)
//
#include <hip/hip_runtime.h>

typedef _Float16 h8 __attribute__((ext_vector_type(8)));
typedef float f4 __attribute__((ext_vector_type(4)));

#define LDS_STRIDE 264   // halfs per LDS row: 528 B, %128 = 16 -> conflict-free b128

// workspace layout (bytes)
constexpr size_t O_W0   = 0;          // swizzled layer0 weights: 98304 halfs  = 196608 B
constexpr size_t O_W1   = 196608;     // swizzled layer1 weights: 131072 halfs = 262144 B
constexpr size_t O_B0   = 458752;     // bias0_eff[512] f32
constexpr size_t O_B1   = 460800;     // bias1_ord[512] f32
constexpr size_t O_PE   = 462848;     // pe_gate[1000][512] f32 = 2048000 B
constexpr size_t O_RING = 2510848;    // h0 ring [32][64][16][128] f16 = 8388608 B
constexpr size_t O_H1   = 10899456;   // h1_last [512][128] f32 = 262144 B
constexpr size_t O_CNT  = 11161600;   // counters: prod[32] (stride 64 ints), cons at +8192 B
constexpr size_t WS_NEED = 11177984;

__device__ __forceinline__ float sigf(float x) { return 1.0f / (1.0f + __expf(-x)); }
__device__ __forceinline__ float tanhfast(float x) {
  float e = __expf(2.0f * x);
  return 1.0f - 2.0f / (e + 1.0f);
}

// ---- precompute: swizzled layer-0 weights (x-side folded through GCN/teacher) ----
// layout: [wave][tile j][kstep][lane][8] halfs ; A-frag A[m=lane&15][k=(lane>>4)*8+e]
// gate rows permuted: p -> (dim d = p>>2, gate e = p&3), orig row = e*128 + d
__global__ void k_wswz0(const float* __restrict__ Wgcn, const float* __restrict__ Wte,
                        const float* __restrict__ Wih0, const float* __restrict__ Whh0,
                        _Float16* __restrict__ out) {
  int tid = blockIdx.x * 256 + threadIdx.x;     // < 98304
  int e8 = tid & 7, lane = (tid >> 3) & 63;
  int rest = tid >> 9;
  int ks = rest % 6; rest /= 6;
  int j = rest & 3, w = rest >> 2;
  int k = ks * 32 + (lane >> 4) * 8 + e8;       // 0..191
  int p = w * 64 + j * 16 + (lane & 15);
  int row = (p & 3) * 128 + (p >> 2);
  float v = 0.f;
  if (k < 32) {
    float s = 0.f;
    for (int dd = 0; dd < 64; dd++)
      s += Wgcn[(k & 15) * 64 + dd] * (Wih0[row * 208 + dd] + Wih0[row * 208 + 64 + dd]);
    v = 0.5f * s;
  } else if (k < 58) {
    float s = 0.f;
    for (int dd = 0; dd < 64; dd++)
      s += Wte[(k - 32) * 64 + dd] * Wih0[row * 208 + 144 + dd];
    v = s;
  } else if (k < 64) {
    v = 0.f;                                    // zero pad 58..63
  } else {
    v = Whh0[row * 128 + (k - 64)];
  }
  out[tid] = (_Float16)v;
}

__global__ void k_wswz1(const float* __restrict__ Wih1, const float* __restrict__ Whh1,
                        _Float16* __restrict__ out) {
  int tid = blockIdx.x * 256 + threadIdx.x;     // < 131072
  int e8 = tid & 7, lane = (tid >> 3) & 63;
  int rest = tid >> 9;
  int ks = rest & 7; rest >>= 3;
  int j = rest & 3, w = rest >> 2;
  int k = ks * 32 + (lane >> 4) * 8 + e8;       // 0..255
  int p = w * 64 + j * 16 + (lane & 15);
  int row = (p & 3) * 128 + (p >> 2);
  float v = (k < 128) ? Wih1[row * 128 + k] : Whh1[row * 128 + (k - 128)];
  out[tid] = (_Float16)v;
}

__global__ void k_bias(const float* __restrict__ bih0, const float* __restrict__ bhh0,
                       const float* __restrict__ bgcn, const float* __restrict__ bte,
                       const float* __restrict__ Wih0,
                       const float* __restrict__ bih1, const float* __restrict__ bhh1,
                       float* __restrict__ bias0, float* __restrict__ bias1) {
  int p = threadIdx.x;                          // 512 threads
  int row = (p & 3) * 128 + (p >> 2);
  float s = bih0[row] + bhh0[row];
  for (int dd = 0; dd < 64; dd++)
    s += bgcn[dd] * (Wih0[row * 208 + dd] + Wih0[row * 208 + 64 + dd]);
  for (int dd = 0; dd < 64; dd++)
    s += bte[dd] * Wih0[row * 208 + 144 + dd];
  bias0[p] = s;
  bias1[p] = bih1[row] + bhh1[row];
}

__global__ void k_pe(const float* __restrict__ Wih0, const float* __restrict__ bias0,
                     float* __restrict__ peg) {
  int tid = blockIdx.x * 256 + threadIdx.x;     // < 512000
  int t = tid >> 9, p = tid & 511;
  int row = (p & 3) * 128 + (p >> 2);
  float acc = bias0[p];
  float tf = (float)t;
  #pragma unroll
  for (int i = 0; i < 8; i++) {
    float div = expf(-1.1512925464970228f * (float)i);  // exp(2i * -ln(10000)/16)
    float ang = tf * div;
    acc += sinf(ang) * Wih0[row * 208 + 128 + 2 * i]
         + cosf(ang) * Wih0[row * 208 + 129 + 2 * i];
  }
  peg[tid] = acc;
}

// ---- persistent LSTM: blocks 0..31 = layer0 producers (A), 32..63 = layer1 consumers (B)
__global__ __launch_bounds__(512, 2) void k_lstm(
    const float* __restrict__ xs, const float* __restrict__ xtc,
    const _Float16* __restrict__ w0g, const _Float16* __restrict__ w1g,
    const float* __restrict__ peg, const float* __restrict__ b1g,
    _Float16* __restrict__ ring, int* cnt, float* __restrict__ h1l) {
  __shared__ __align__(16) _Float16 sm[16 * LDS_STRIDE];
  const int tidx = threadIdx.x;
  const int lane = tidx & 63;
  const int wv = tidx >> 6;       // wave 0..7
  const int q = lane >> 4;        // quad
  const int mcol = lane & 15;     // batch col for B-frag & C/D col

  for (int i = tidx; i < 16 * LDS_STRIDE; i += 512) sm[i] = (_Float16)0.f;
  const f4 z4 = {0.f, 0.f, 0.f, 0.f};

  if (blockIdx.x < 32) {
    // ============== role A: layer 0 ==============
    const int g = blockIdx.x;
    h8 wf[4][6];
    #pragma unroll
    for (int j = 0; j < 4; j++)
      #pragma unroll
      for (int ks = 0; ks < 6; ks++)
        wf[j][ks] = ((const h8*)w0g)[(((wv * 4 + j) * 6 + ks) << 6) + lane];
    float c0[4] = {0.f, 0.f, 0.f, 0.f};
    const int tm = tidx / 26;
    const int tc = tidx - tm * 26;
    int* prod = cnt + g * 64;
    int* cons = cnt + 2048 + g * 64;
    __syncthreads();
    // x(0) -> LDS (k 0..57; 58..63 stay zero)
    if (tidx < 256) {
      float2 v = *(const float2*)(xs + ((size_t)(g * 16 + (tidx >> 4)) * 1000 + 0) * 32 + 2 * (tidx & 15));
      sm[(tidx >> 4) * LDS_STRIDE + 2 * (tidx & 15)]     = (_Float16)v.x;
      sm[(tidx >> 4) * LDS_STRIDE + 2 * (tidx & 15) + 1] = (_Float16)v.y;
    }
    if (tidx < 416) {
      float v = xtc[((size_t)(g * 16 + tm) * 1000 + 0) * 26 + tc];
      sm[tm * LDS_STRIDE + 32 + tc] = (_Float16)v;
    }
    __syncthreads();
    #pragma unroll 1
    for (int t = 0; t < 1000; t++) {
      // ring-full guard (checked every 16 steps; ring depth 64, cons lags <=16)
      if ((t & 15) == 0 && t >= 64) {
        int gd = 0;
        while (__hip_atomic_load(cons, __ATOMIC_RELAXED, __HIP_MEMORY_SCOPE_AGENT) < t - 48) {
          __builtin_amdgcn_s_sleep(8);
          if (++gd > 50000000) break;
        }
      }
      // prefetch x(t+1)
      const int tn = (t < 999) ? t + 1 : 999;
      float2 xsv = {0.f, 0.f};
      float xtv = 0.f;
      if (tidx < 256) xsv = *(const float2*)(xs + ((size_t)(g * 16 + (tidx >> 4)) * 1000 + tn) * 32 + 2 * (tidx & 15));
      if (tidx < 416) xtv = xtc[((size_t)(g * 16 + tm) * 1000 + tn) * 26 + tc];
      // pe+bias gates for this t (rows permuted; 4 consecutive = i,f,g,o of one dim)
      f4 pe[4];
      #pragma unroll
      for (int j = 0; j < 4; j++)
        pe[j] = *(const f4*)(peg + (size_t)t * 512 + wv * 64 + j * 16 + q * 4);
      // z = Wcat0 * [x(t); h0(t-1)]
      f4 acc[4] = {z4, z4, z4, z4};
      #pragma unroll
      for (int ks = 0; ks < 6; ks++) {
        h8 bf = *(const h8*)(sm + mcol * LDS_STRIDE + ks * 32 + q * 8);
        #pragma unroll
        for (int j = 0; j < 4; j++)
          acc[j] = __builtin_amdgcn_mfma_f32_16x16x32_f16(wf[j][ks], bf, acc[j], 0, 0, 0);
      }
      _Float16 hv[4];
      #pragma unroll
      for (int j = 0; j < 4; j++) {
        float zi = acc[j][0] + pe[j][0];
        float zf = acc[j][1] + pe[j][1];
        float zg = acc[j][2] + pe[j][2];
        float zo = acc[j][3] + pe[j][3];
        float cc = sigf(zf) * c0[j] + sigf(zi) * tanhfast(zg);
        c0[j] = cc;
        hv[j] = (_Float16)(sigf(zo) * tanhfast(cc));
      }
      // publish h0(t) to ring [m][d]
      _Float16* slot = ring + ((size_t)(g * 64 + (t & 63)) << 11);
      #pragma unroll
      for (int j = 0; j < 4; j++)
        slot[(mcol << 7) + wv * 16 + j * 4 + q] = hv[j];
      __syncthreads();   // S1: all MFMA LDS reads of step t done
      #pragma unroll
      for (int j = 0; j < 4; j++)
        sm[mcol * LDS_STRIDE + 64 + wv * 16 + j * 4 + q] = hv[j];
      if (tidx < 256) {
        sm[(tidx >> 4) * LDS_STRIDE + 2 * (tidx & 15)]     = (_Float16)xsv.x;
        sm[(tidx >> 4) * LDS_STRIDE + 2 * (tidx & 15) + 1] = (_Float16)xsv.y;
      }
      if (tidx < 416) sm[tm * LDS_STRIDE + 32 + tc] = (_Float16)xtv;
      __threadfence();   // drain ring stores to device scope
      __syncthreads();   // S2: LDS ready for t+1, all threads fenced
      if (tidx == 0)
        __hip_atomic_store(prod, t + 1, __ATOMIC_RELEASE, __HIP_MEMORY_SCOPE_AGENT);
    }
  } else {
    // ============== role B: layer 1 ==============
    const int g = blockIdx.x - 32;
    h8 wf[4][8];
    #pragma unroll
    for (int j = 0; j < 4; j++)
      #pragma unroll
      for (int ks = 0; ks < 8; ks++)
        wf[j][ks] = ((const h8*)w1g)[(((wv * 4 + j) * 8 + ks) << 6) + lane];
    f4 bias[4];
    #pragma unroll
    for (int j = 0; j < 4; j++)
      bias[j] = *(const f4*)(b1g + wv * 64 + j * 16 + q * 4);
    float c1[4] = {0.f, 0.f, 0.f, 0.f};
    int* prod = cnt + g * 64;
    int* cons = cnt + 2048 + g * 64;
    __syncthreads();
    #pragma unroll 1
    for (int t = 0; t < 1000; t++) {
      int gd = 0;
      while (__hip_atomic_load(prod, __ATOMIC_ACQUIRE, __HIP_MEMORY_SCOPE_AGENT) < t + 1) {
        __builtin_amdgcn_s_sleep(2);
        if (++gd > 100000000) break;
      }
      // ring h0(t) load in flight while we do the h1-dependent k-steps
      unsigned long long rv =
          *(const unsigned long long*)(ring + (((size_t)(g * 64 + (t & 63))) << 11) + tidx * 4);
      f4 acc[4] = {z4, z4, z4, z4};
      #pragma unroll
      for (int ks = 4; ks < 8; ks++) {   // Whh1 * h1(t-1): k 128..255 (written last iter, ordered by end barrier)
        h8 bf = *(const h8*)(sm + mcol * LDS_STRIDE + ks * 32 + q * 8);
        #pragma unroll
        for (int j = 0; j < 4; j++)
          acc[j] = __builtin_amdgcn_mfma_f32_16x16x32_f16(wf[j][ks], bf, acc[j], 0, 0, 0);
      }
      *(unsigned long long*)(sm + (tidx >> 5) * LDS_STRIDE + (tidx & 31) * 4) = rv;  // h0 -> k 0..127
      __syncthreads();   // S1
      #pragma unroll
      for (int ks = 0; ks < 4; ks++) {   // Wih1 * h0(t)
        h8 bf = *(const h8*)(sm + mcol * LDS_STRIDE + ks * 32 + q * 8);
        #pragma unroll
        for (int j = 0; j < 4; j++)
          acc[j] = __builtin_amdgcn_mfma_f32_16x16x32_f16(wf[j][ks], bf, acc[j], 0, 0, 0);
      }
      _Float16 hv[4];
      float hf[4];
      #pragma unroll
      for (int j = 0; j < 4; j++) {
        float zi = acc[j][0] + bias[j][0];
        float zf = acc[j][1] + bias[j][1];
        float zg = acc[j][2] + bias[j][2];
        float zo = acc[j][3] + bias[j][3];
        float cc = sigf(zf) * c1[j] + sigf(zi) * tanhfast(zg);
        c1[j] = cc;
        hf[j] = sigf(zo) * tanhfast(cc);
        hv[j] = (_Float16)hf[j];
      }
      #pragma unroll
      for (int j = 0; j < 4; j++)
        sm[mcol * LDS_STRIDE + 128 + wv * 16 + j * 4 + q] = hv[j];   // h1(t) (disjoint from k0..127 reads)
      if (t == 999) {
        #pragma unroll
        for (int j = 0; j < 4; j++)
          h1l[((size_t)(g * 16 + mcol) << 7) + wv * 16 + j * 4 + q] = hf[j];
      }
      if ((t & 15) == 15 && tidx == 0)
        __hip_atomic_store(cons, t + 1, __ATOMIC_RELEASE, __HIP_MEMORY_SCOPE_AGENT);
      __syncthreads();   // S2: h1(t) visible before next iter's ks4..7 reads
    }
  }
}

// ---- MLP head: one block per batch row ----
__global__ void k_mlp(const float* __restrict__ h1l,
                      const float* __restrict__ W1, const float* __restrict__ b1,
                      const float* __restrict__ W2, const float* __restrict__ b2,
                      const float* __restrict__ W3, const float* __restrict__ b3,
                      float* __restrict__ out) {
  __shared__ float sh[128];
  __shared__ float sy1[128];
  __shared__ float sy2[64];
  const int b = blockIdx.x;
  const int t = threadIdx.x;   // 128 threads
  sh[t] = h1l[b * 128 + t];
  __syncthreads();
  {
    float s = b1[t];
    const float* wr = W1 + t * 128;
    for (int k = 0; k < 128; k++) s += sh[k] * wr[k];
    sy1[t] = fmaxf(s, 0.f);
  }
  __syncthreads();
  if (t < 64) {
    float s = b2[t];
    const float* wr = W2 + t * 128;
    for (int k = 0; k < 128; k++) s += sy1[k] * wr[k];
    sy2[t] = fmaxf(s, 0.f);
  }
  __syncthreads();
  if (t < 26) {
    float s = b3[t];
    const float* wr = W3 + t * 64;
    for (int k = 0; k < 64; k++) s += sy2[k] * wr[k];
    out[b * 26 + t] = s;
  }
}

extern "C" void kernel_launch(void* const* d_in, const int* in_sizes, int n_in,
                              void* d_out, int out_size, void* d_ws, size_t ws_size,
                              hipStream_t stream) {
  const float* xs   = (const float*)d_in[0];
  const float* xtc  = (const float*)d_in[1];
  const float* Wgcn = (const float*)d_in[2];
  const float* bgcn = (const float*)d_in[3];
  const float* Wte  = (const float*)d_in[4];
  const float* bte  = (const float*)d_in[5];
  const float* Wih0 = (const float*)d_in[6];
  const float* Whh0 = (const float*)d_in[7];
  const float* bih0 = (const float*)d_in[8];
  const float* bhh0 = (const float*)d_in[9];
  const float* Wih1 = (const float*)d_in[10];
  const float* Whh1 = (const float*)d_in[11];
  const float* bih1 = (const float*)d_in[12];
  const float* bhh1 = (const float*)d_in[13];
  const float* W1   = (const float*)d_in[14];
  const float* b1   = (const float*)d_in[15];
  const float* W2   = (const float*)d_in[16];
  const float* b2   = (const float*)d_in[17];
  const float* W3   = (const float*)d_in[18];
  const float* b3   = (const float*)d_in[19];

  char* ws = (char*)d_ws;
  if (ws_size < WS_NEED) return;

  _Float16* w0   = (_Float16*)(ws + O_W0);
  _Float16* w1   = (_Float16*)(ws + O_W1);
  float* bias0   = (float*)(ws + O_B0);
  float* bias1   = (float*)(ws + O_B1);
  float* peg     = (float*)(ws + O_PE);
  _Float16* ring = (_Float16*)(ws + O_RING);
  float* h1l     = (float*)(ws + O_H1);
  int* cnt       = (int*)(ws + O_CNT);

  hipMemsetAsync(ws + O_CNT, 0, 16384, stream);
  hipLaunchKernelGGL(k_wswz0, dim3(384), dim3(256), 0, stream, Wgcn, Wte, Wih0, Whh0, w0);
  hipLaunchKernelGGL(k_wswz1, dim3(512), dim3(256), 0, stream, Wih1, Whh1, w1);
  hipLaunchKernelGGL(k_bias, dim3(1), dim3(512), 0, stream, bih0, bhh0, bgcn, bte, Wih0, bih1, bhh1, bias0, bias1);
  hipLaunchKernelGGL(k_pe, dim3(2000), dim3(256), 0, stream, Wih0, bias0, peg);
  hipLaunchKernelGGL(k_lstm, dim3(64), dim3(512), 0, stream, xs, xtc, w0, w1, peg, bias1, ring, cnt, h1l);
  hipLaunchKernelGGL(k_mlp, dim3(512), dim3(128), 0, stream, h1l, W1, b1, W2, b2, W3, b3, (float*)d_out);
}

// Round 2
// 10867.062 us; speedup vs baseline: 1.0000x; 1.0000x over previous
//
#include <hip/hip_runtime.h>

typedef _Float16 h8 __attribute__((ext_vector_type(8)));
typedef _Float16 h4v __attribute__((ext_vector_type(4)));
typedef float f4 __attribute__((ext_vector_type(4)));

#define LDS_STRIDE 264   // halfs per LDS row: 528 B -> 2-way bank alias only (free)

// ---------------- workspace layouts ----------------
// small (fallback, round-1 proven) layout
constexpr size_t O_W0   = 0;
constexpr size_t O_W1   = 196608;
constexpr size_t O_B0   = 458752;
constexpr size_t O_B1   = 460800;
constexpr size_t O_PE   = 462848;
constexpr size_t O_RING = 2510848;
constexpr size_t O_H1   = 10899456;
constexpr size_t O_CNT  = 11161600;
constexpr size_t WS_NEED = 11177984;

// big (fused ZX) layout
constexpr size_t O2_W0H = 0;           // Whh0 swizzled: 65536 halfs = 131072 B
constexpr size_t O2_W1  = 131072;      // [Wih1|Whh1] swizzled: 131072 halfs = 262144 B
constexpr size_t O2_WX  = 393216;      // x-side weights swizzled: 32768 halfs = 65536 B
constexpr size_t O2_B0  = 458752;      // bias0_eff[512] f32
constexpr size_t O2_B1  = 460800;      // bias1_ord[512] f32
constexpr size_t O2_PE  = 462848;      // pe_gate[1000][512] f32 (incl bias0)
constexpr size_t O2_H1  = 2510848;     // h1_last [512][128] f32
constexpr size_t O2_ZX  = 2773248;     // ZX[t][g][dd][m][e] f16 = 524288000 B
constexpr size_t WS2_NEED = 2773248 + 524288000ull;

__device__ __forceinline__ float sigf(float x) { return 1.0f / (1.0f + __expf(-x)); }
__device__ __forceinline__ float tanhfast(float x) {
  float e = __expf(2.0f * x);
  return 1.0f - 2.0f / (e + 1.0f);
}
// barrier that drains LDS only (keeps global prefetch loads in flight)
__device__ __forceinline__ void bar_lds() {
  asm volatile("s_waitcnt lgkmcnt(0)\n\ts_barrier" ::: "memory");
}

// =======================================================================
// shared precompute kernels (both paths)
// =======================================================================
__global__ void k_wswz1(const float* __restrict__ Wih1, const float* __restrict__ Whh1,
                        _Float16* __restrict__ out) {
  int tid = blockIdx.x * 256 + threadIdx.x;     // < 131072
  int e8 = tid & 7, lane = (tid >> 3) & 63;
  int rest = tid >> 9;
  int ks = rest & 7; rest >>= 3;
  int j = rest & 3, w = rest >> 2;
  int k = ks * 32 + (lane >> 4) * 8 + e8;       // 0..255
  int p = w * 64 + j * 16 + (lane & 15);
  int row = (p & 3) * 128 + (p >> 2);
  float v = (k < 128) ? Wih1[row * 128 + k] : Whh1[row * 128 + (k - 128)];
  out[tid] = (_Float16)v;
}

__global__ void k_bias(const float* __restrict__ bih0, const float* __restrict__ bhh0,
                       const float* __restrict__ bgcn, const float* __restrict__ bte,
                       const float* __restrict__ Wih0,
                       const float* __restrict__ bih1, const float* __restrict__ bhh1,
                       float* __restrict__ bias0, float* __restrict__ bias1) {
  int p = threadIdx.x;                          // 512 threads
  int row = (p & 3) * 128 + (p >> 2);
  float s = bih0[row] + bhh0[row];
  for (int dd = 0; dd < 64; dd++)
    s += bgcn[dd] * (Wih0[row * 208 + dd] + Wih0[row * 208 + 64 + dd]);
  for (int dd = 0; dd < 64; dd++)
    s += bte[dd] * Wih0[row * 208 + 144 + dd];
  bias0[p] = s;
  bias1[p] = bih1[row] + bhh1[row];
}

__global__ void k_pe(const float* __restrict__ Wih0, const float* __restrict__ bias0,
                     float* __restrict__ peg) {
  int tid = blockIdx.x * 256 + threadIdx.x;     // < 512000
  int t = tid >> 9, p = tid & 511;
  int row = (p & 3) * 128 + (p >> 2);
  float acc = bias0[p];
  float tf = (float)t;
  #pragma unroll
  for (int i = 0; i < 8; i++) {
    float div = expf(-1.1512925464970228f * (float)i);  // exp(2i * -ln(10000)/16)
    float ang = tf * div;
    acc += sinf(ang) * Wih0[row * 208 + 128 + 2 * i]
         + cosf(ang) * Wih0[row * 208 + 129 + 2 * i];
  }
  peg[tid] = acc;
}

// ---- MLP head: one block per batch row ----
__global__ void k_mlp(const float* __restrict__ h1l,
                      const float* __restrict__ W1, const float* __restrict__ b1,
                      const float* __restrict__ W2, const float* __restrict__ b2,
                      const float* __restrict__ W3, const float* __restrict__ b3,
                      float* __restrict__ out) {
  __shared__ float sh[128];
  __shared__ float sy1[128];
  __shared__ float sy2[64];
  const int b = blockIdx.x;
  const int t = threadIdx.x;   // 128 threads
  sh[t] = h1l[b * 128 + t];
  __syncthreads();
  {
    float s = b1[t];
    const float* wr = W1 + t * 128;
    for (int k = 0; k < 128; k++) s += sh[k] * wr[k];
    sy1[t] = fmaxf(s, 0.f);
  }
  __syncthreads();
  if (t < 64) {
    float s = b2[t];
    const float* wr = W2 + t * 128;
    for (int k = 0; k < 128; k++) s += sy1[k] * wr[k];
    sy2[t] = fmaxf(s, 0.f);
  }
  __syncthreads();
  if (t < 26) {
    float s = b3[t];
    const float* wr = W3 + t * 64;
    for (int k = 0; k < 64; k++) s += sy2[k] * wr[k];
    out[b * 26 + t] = s;
  }
}

// =======================================================================
// BIG PATH: fused single-block-per-group LSTM + ZX precompute
// =======================================================================

// Whh0 swizzled as A-frags: [wv 8][j 4][ks 4][lane][8]
__global__ void k_wswz0b(const float* __restrict__ Whh0, _Float16* __restrict__ out) {
  int tid = blockIdx.x * 256 + threadIdx.x;     // < 65536
  int e8 = tid & 7, lane = (tid >> 3) & 63;
  int rest = tid >> 9;
  int ks = rest & 3; rest >>= 2;
  int j = rest & 3, wv = rest >> 2;
  int k = ks * 32 + (lane >> 4) * 8 + e8;       // 0..127
  int p = wv * 64 + j * 16 + (lane & 15);
  int row = (p & 3) * 128 + (p >> 2);
  out[tid] = (_Float16)Whh0[row * 128 + k];
}

// x-side effective weights (GCN-folded student 16 + teacher 26, pad 64)
// A-frags for k_zx: [wv2 4][j 8][ks 2][lane][8]
__global__ void k_wswzx(const float* __restrict__ Wgcn, const float* __restrict__ Wte,
                        const float* __restrict__ Wih0, _Float16* __restrict__ out) {
  int tid = blockIdx.x * 256 + threadIdx.x;     // < 32768
  int e8 = tid & 7, lane = (tid >> 3) & 63;
  int rest = tid >> 9;
  int ks = rest & 1; rest >>= 1;
  int j = rest & 7, wv2 = rest >> 3;
  int k = ks * 32 + (lane >> 4) * 8 + e8;       // 0..63
  int p = wv2 * 128 + j * 16 + (lane & 15);
  int row = (p & 3) * 128 + (p >> 2);
  float v = 0.f;
  if (k < 16) {
    float s = 0.f;
    for (int dd = 0; dd < 64; dd++)
      s += Wgcn[k * 64 + dd] * (Wih0[row * 208 + dd] + Wih0[row * 208 + 64 + dd]);
    v = 0.5f * s;
  } else if (k < 42) {
    float s = 0.f;
    for (int dd = 0; dd < 64; dd++)
      s += Wte[(k - 16) * 64 + dd] * Wih0[row * 208 + 144 + dd];
    v = s;
  }
  out[tid] = (_Float16)v;
}

// ZX[t][g 32][dd 128][m 16][e 4] f16 : all non-recurrent layer-0 gate terms
__global__ __launch_bounds__(256) void k_zx(
    const float* __restrict__ xs, const float* __restrict__ xtc,
    const _Float16* __restrict__ wxs, const float* __restrict__ peg,
    _Float16* __restrict__ zxo) {
  const int t = blockIdx.x;
  __shared__ __align__(16) _Float16 xl[512 * 72];   // 73728 B
  const int tid = threadIdx.x, lane = tid & 63, wv2 = tid >> 6;
  const int q = lane >> 4, m = lane & 15;
  for (int i = tid; i < 512 * 16; i += 256) {
    int b = i >> 4, c = i & 15;
    const float* xb = xs + ((size_t)b * 1000 + t) * 32;
    xl[b * 72 + c] = (_Float16)(xb[c] + xb[16 + c]);
  }
  for (int i = tid; i < 512 * 26; i += 256) {
    int b = i / 26, c = i - b * 26;
    xl[b * 72 + 16 + c] = (_Float16)xtc[((size_t)b * 1000 + t) * 26 + c];
  }
  for (int i = tid; i < 512 * 30; i += 256) {
    int b = i / 30, c = i - b * 30;
    xl[b * 72 + 42 + c] = (_Float16)0.f;
  }
  h8 wf[8][2];
  #pragma unroll
  for (int j = 0; j < 8; j++)
    #pragma unroll
    for (int ks = 0; ks < 2; ks++)
      wf[j][ks] = ((const h8*)wxs)[((wv2 * 8 + j) * 2 + ks) * 64 + lane];
  f4 pv[8];
  #pragma unroll
  for (int j = 0; j < 8; j++)
    pv[j] = *(const f4*)(peg + (size_t)t * 512 + wv2 * 128 + j * 16 + q * 4);
  __syncthreads();
  const f4 z4 = {0.f, 0.f, 0.f, 0.f};
  #pragma unroll 1
  for (int nt = 0; nt < 32; nt++) {
    h8 b0 = *(const h8*)(xl + (nt * 16 + m) * 72 + q * 8);
    h8 b1 = *(const h8*)(xl + (nt * 16 + m) * 72 + 32 + q * 8);
    #pragma unroll
    for (int j = 0; j < 8; j++) {
      f4 a = __builtin_amdgcn_mfma_f32_16x16x32_f16(wf[j][0], b0, z4, 0, 0, 0);
      a = __builtin_amdgcn_mfma_f32_16x16x32_f16(wf[j][1], b1, a, 0, 0, 0);
      a += pv[j];
      int dd = wv2 * 32 + j * 4 + q;
      h4v o = {(_Float16)a[0], (_Float16)a[1], (_Float16)a[2], (_Float16)a[3]};
      *(h4v*)(zxo + ((((size_t)t * 32 + nt) * 128 + dd) * 16 + m) * 4) = o;
    }
  }
}

// fused 2-layer LSTM: 32 blocks x 512 threads; all h exchange via LDS
__global__ __launch_bounds__(512, 2) void k_lstm2(
    const _Float16* __restrict__ zx, const _Float16* __restrict__ w0s,
    const _Float16* __restrict__ w1s, const float* __restrict__ b1g,
    float* __restrict__ h1l) {
  __shared__ __align__(16) _Float16 sm[16 * LDS_STRIDE + 1024];
  float* bsm = (float*)(sm + 16 * LDS_STRIDE);
  const int tidx = threadIdx.x;
  const int lane = tidx & 63;
  const int wv = tidx >> 6;
  const int q = lane >> 4;
  const int mcol = lane & 15;
  const int g = blockIdx.x;

  for (int i = tidx; i < 16 * LDS_STRIDE; i += 512) sm[i] = (_Float16)0.f;
  bsm[tidx] = b1g[tidx];

  h8 w0h[4][4];
  #pragma unroll
  for (int j = 0; j < 4; j++)
    #pragma unroll
    for (int ks = 0; ks < 4; ks++)
      w0h[j][ks] = ((const h8*)w0s)[((wv * 4 + j) * 4 + ks) * 64 + lane];
  h8 w1[4][8];
  #pragma unroll
  for (int j = 0; j < 4; j++)
    #pragma unroll
    for (int ks = 0; ks < 8; ks++)
      w1[j][ks] = ((const h8*)w1s)[((wv * 4 + j) * 8 + ks) * 64 + lane];

  float c0[4] = {0.f, 0.f, 0.f, 0.f};
  float c1[4] = {0.f, 0.f, 0.f, 0.f};
  float hf1[4] = {0.f, 0.f, 0.f, 0.f};
  const f4 z4 = {0.f, 0.f, 0.f, 0.f};

  // zx address: halfs = t*262144 + g*8192 + dd*64 + mcol*4 ; dd = wv*16 + j*4 + q
  const _Float16* zp = zx + (size_t)g * 8192 + (size_t)(wv * 16 + q) * 64 + mcol * 4;
  h4v zn[4];
  #pragma unroll
  for (int j = 0; j < 4; j++) zn[j] = *(const h4v*)(zp + j * 256);

  __syncthreads();

  #pragma unroll 1
  for (int t = 0; t < 1000; t++) {
    h4v zc[4];
    #pragma unroll
    for (int j = 0; j < 4; j++) zc[j] = zn[j];
    if (t < 999) {
      const _Float16* zpn = zp + (size_t)(t + 1) * 262144;
      #pragma unroll
      for (int j = 0; j < 4; j++) zn[j] = *(const h4v*)(zpn + j * 256);
    }
    // ---- layer 0: z = Whh0*h0(t-1) + zx(t) ----
    f4 acc[4] = {z4, z4, z4, z4};
    #pragma unroll
    for (int ks = 0; ks < 4; ks++) {
      h8 bf = *(const h8*)(sm + mcol * LDS_STRIDE + ks * 32 + q * 8);
      #pragma unroll
      for (int j = 0; j < 4; j++)
        acc[j] = __builtin_amdgcn_mfma_f32_16x16x32_f16(w0h[j][ks], bf, acc[j], 0, 0, 0);
    }
    _Float16 hv0[4];
    #pragma unroll
    for (int j = 0; j < 4; j++) {
      float zi = acc[j][0] + (float)zc[j][0];
      float zf = acc[j][1] + (float)zc[j][1];
      float zg = acc[j][2] + (float)zc[j][2];
      float zo = acc[j][3] + (float)zc[j][3];
      float cc = sigf(zf) * c0[j] + sigf(zi) * tanhfast(zg);
      c0[j] = cc;
      hv0[j] = (_Float16)(sigf(zo) * tanhfast(cc));
    }
    bar_lds();   // S1: all layer-0 reads of h0(t-1) done
    #pragma unroll
    for (int j = 0; j < 4; j++)
      sm[mcol * LDS_STRIDE + wv * 16 + j * 4 + q] = hv0[j];
    bar_lds();   // S2: h0(t) visible
    // ---- layer 1: z = Wih1*h0(t) + Whh1*h1(t-1) + b1 ----
    f4 a1[4] = {z4, z4, z4, z4};
    #pragma unroll
    for (int ks = 0; ks < 8; ks++) {
      h8 bf = *(const h8*)(sm + mcol * LDS_STRIDE + ks * 32 + q * 8);
      #pragma unroll
      for (int j = 0; j < 4; j++)
        a1[j] = __builtin_amdgcn_mfma_f32_16x16x32_f16(w1[j][ks], bf, a1[j], 0, 0, 0);
    }
    _Float16 hv1[4];
    #pragma unroll
    for (int j = 0; j < 4; j++) {
      f4 bj = *(const f4*)(bsm + wv * 64 + j * 16 + q * 4);
      float zi = a1[j][0] + bj[0];
      float zf = a1[j][1] + bj[1];
      float zg = a1[j][2] + bj[2];
      float zo = a1[j][3] + bj[3];
      float cc = sigf(zf) * c1[j] + sigf(zi) * tanhfast(zg);
      c1[j] = cc;
      float h = sigf(zo) * tanhfast(cc);
      hf1[j] = h;
      hv1[j] = (_Float16)h;
    }
    bar_lds();   // S3: all layer-1 reads done
    #pragma unroll
    for (int j = 0; j < 4; j++)
      sm[mcol * LDS_STRIDE + 128 + wv * 16 + j * 4 + q] = hv1[j];
  }
  #pragma unroll
  for (int j = 0; j < 4; j++)
    h1l[((size_t)(g * 16 + mcol)) * 128 + wv * 16 + j * 4 + q] = hf1[j];
}

// =======================================================================
// FALLBACK PATH (round-1, proven): kept verbatim
// =======================================================================
__global__ void k_wswz0(const float* __restrict__ Wgcn, const float* __restrict__ Wte,
                        const float* __restrict__ Wih0, const float* __restrict__ Whh0,
                        _Float16* __restrict__ out) {
  int tid = blockIdx.x * 256 + threadIdx.x;     // < 98304
  int e8 = tid & 7, lane = (tid >> 3) & 63;
  int rest = tid >> 9;
  int ks = rest % 6; rest /= 6;
  int j = rest & 3, w = rest >> 2;
  int k = ks * 32 + (lane >> 4) * 8 + e8;       // 0..191
  int p = w * 64 + j * 16 + (lane & 15);
  int row = (p & 3) * 128 + (p >> 2);
  float v = 0.f;
  if (k < 32) {
    float s = 0.f;
    for (int dd = 0; dd < 64; dd++)
      s += Wgcn[(k & 15) * 64 + dd] * (Wih0[row * 208 + dd] + Wih0[row * 208 + 64 + dd]);
    v = 0.5f * s;
  } else if (k < 58) {
    float s = 0.f;
    for (int dd = 0; dd < 64; dd++)
      s += Wte[(k - 32) * 64 + dd] * Wih0[row * 208 + 144 + dd];
    v = s;
  } else if (k < 64) {
    v = 0.f;
  } else {
    v = Whh0[row * 128 + (k - 64)];
  }
  out[tid] = (_Float16)v;
}

__global__ __launch_bounds__(512, 2) void k_lstm(
    const float* __restrict__ xs, const float* __restrict__ xtc,
    const _Float16* __restrict__ w0g, const _Float16* __restrict__ w1g,
    const float* __restrict__ peg, const float* __restrict__ b1g,
    _Float16* __restrict__ ring, int* cnt, float* __restrict__ h1l) {
  __shared__ __align__(16) _Float16 sm[16 * LDS_STRIDE];
  const int tidx = threadIdx.x;
  const int lane = tidx & 63;
  const int wv = tidx >> 6;
  const int q = lane >> 4;
  const int mcol = lane & 15;

  for (int i = tidx; i < 16 * LDS_STRIDE; i += 512) sm[i] = (_Float16)0.f;
  const f4 z4 = {0.f, 0.f, 0.f, 0.f};

  if (blockIdx.x < 32) {
    const int g = blockIdx.x;
    h8 wf[4][6];
    #pragma unroll
    for (int j = 0; j < 4; j++)
      #pragma unroll
      for (int ks = 0; ks < 6; ks++)
        wf[j][ks] = ((const h8*)w0g)[(((wv * 4 + j) * 6 + ks) << 6) + lane];
    float c0[4] = {0.f, 0.f, 0.f, 0.f};
    const int tm = tidx / 26;
    const int tc = tidx - tm * 26;
    int* prod = cnt + g * 64;
    int* cons = cnt + 2048 + g * 64;
    __syncthreads();
    if (tidx < 256) {
      float2 v = *(const float2*)(xs + ((size_t)(g * 16 + (tidx >> 4)) * 1000 + 0) * 32 + 2 * (tidx & 15));
      sm[(tidx >> 4) * LDS_STRIDE + 2 * (tidx & 15)]     = (_Float16)v.x;
      sm[(tidx >> 4) * LDS_STRIDE + 2 * (tidx & 15) + 1] = (_Float16)v.y;
    }
    if (tidx < 416) {
      float v = xtc[((size_t)(g * 16 + tm) * 1000 + 0) * 26 + tc];
      sm[tm * LDS_STRIDE + 32 + tc] = (_Float16)v;
    }
    __syncthreads();
    #pragma unroll 1
    for (int t = 0; t < 1000; t++) {
      if ((t & 15) == 0 && t >= 64) {
        int gd = 0;
        while (__hip_atomic_load(cons, __ATOMIC_RELAXED, __HIP_MEMORY_SCOPE_AGENT) < t - 48) {
          __builtin_amdgcn_s_sleep(8);
          if (++gd > 50000000) break;
        }
      }
      const int tn = (t < 999) ? t + 1 : 999;
      float2 xsv = {0.f, 0.f};
      float xtv = 0.f;
      if (tidx < 256) xsv = *(const float2*)(xs + ((size_t)(g * 16 + (tidx >> 4)) * 1000 + tn) * 32 + 2 * (tidx & 15));
      if (tidx < 416) xtv = xtc[((size_t)(g * 16 + tm) * 1000 + tn) * 26 + tc];
      f4 pe[4];
      #pragma unroll
      for (int j = 0; j < 4; j++)
        pe[j] = *(const f4*)(peg + (size_t)t * 512 + wv * 64 + j * 16 + q * 4);
      f4 acc[4] = {z4, z4, z4, z4};
      #pragma unroll
      for (int ks = 0; ks < 6; ks++) {
        h8 bf = *(const h8*)(sm + mcol * LDS_STRIDE + ks * 32 + q * 8);
        #pragma unroll
        for (int j = 0; j < 4; j++)
          acc[j] = __builtin_amdgcn_mfma_f32_16x16x32_f16(wf[j][ks], bf, acc[j], 0, 0, 0);
      }
      _Float16 hv[4];
      #pragma unroll
      for (int j = 0; j < 4; j++) {
        float zi = acc[j][0] + pe[j][0];
        float zf = acc[j][1] + pe[j][1];
        float zg = acc[j][2] + pe[j][2];
        float zo = acc[j][3] + pe[j][3];
        float cc = sigf(zf) * c0[j] + sigf(zi) * tanhfast(zg);
        c0[j] = cc;
        hv[j] = (_Float16)(sigf(zo) * tanhfast(cc));
      }
      _Float16* slot = ring + ((size_t)(g * 64 + (t & 63)) << 11);
      #pragma unroll
      for (int j = 0; j < 4; j++)
        slot[(mcol << 7) + wv * 16 + j * 4 + q] = hv[j];
      __syncthreads();
      #pragma unroll
      for (int j = 0; j < 4; j++)
        sm[mcol * LDS_STRIDE + 64 + wv * 16 + j * 4 + q] = hv[j];
      if (tidx < 256) {
        sm[(tidx >> 4) * LDS_STRIDE + 2 * (tidx & 15)]     = (_Float16)xsv.x;
        sm[(tidx >> 4) * LDS_STRIDE + 2 * (tidx & 15) + 1] = (_Float16)xsv.y;
      }
      if (tidx < 416) sm[tm * LDS_STRIDE + 32 + tc] = (_Float16)xtv;
      __threadfence();
      __syncthreads();
      if (tidx == 0)
        __hip_atomic_store(prod, t + 1, __ATOMIC_RELEASE, __HIP_MEMORY_SCOPE_AGENT);
    }
  } else {
    const int g = blockIdx.x - 32;
    h8 wf[4][8];
    #pragma unroll
    for (int j = 0; j < 4; j++)
      #pragma unroll
      for (int ks = 0; ks < 8; ks++)
        wf[j][ks] = ((const h8*)w1g)[(((wv * 4 + j) * 8 + ks) << 6) + lane];
    f4 bias[4];
    #pragma unroll
    for (int j = 0; j < 4; j++)
      bias[j] = *(const f4*)(b1g + wv * 64 + j * 16 + q * 4);
    float c1[4] = {0.f, 0.f, 0.f, 0.f};
    int* prod = cnt + g * 64;
    int* cons = cnt + 2048 + g * 64;
    __syncthreads();
    #pragma unroll 1
    for (int t = 0; t < 1000; t++) {
      int gd = 0;
      while (__hip_atomic_load(prod, __ATOMIC_ACQUIRE, __HIP_MEMORY_SCOPE_AGENT) < t + 1) {
        __builtin_amdgcn_s_sleep(2);
        if (++gd > 100000000) break;
      }
      unsigned long long rv =
          *(const unsigned long long*)(ring + (((size_t)(g * 64 + (t & 63))) << 11) + tidx * 4);
      f4 acc[4] = {z4, z4, z4, z4};
      #pragma unroll
      for (int ks = 4; ks < 8; ks++) {
        h8 bf = *(const h8*)(sm + mcol * LDS_STRIDE + ks * 32 + q * 8);
        #pragma unroll
        for (int j = 0; j < 4; j++)
          acc[j] = __builtin_amdgcn_mfma_f32_16x16x32_f16(wf[j][ks], bf, acc[j], 0, 0, 0);
      }
      *(unsigned long long*)(sm + (tidx >> 5) * LDS_STRIDE + (tidx & 31) * 4) = rv;
      __syncthreads();
      #pragma unroll
      for (int ks = 0; ks < 4; ks++) {
        h8 bf = *(const h8*)(sm + mcol * LDS_STRIDE + ks * 32 + q * 8);
        #pragma unroll
        for (int j = 0; j < 4; j++)
          acc[j] = __builtin_amdgcn_mfma_f32_16x16x32_f16(wf[j][ks], bf, acc[j], 0, 0, 0);
      }
      _Float16 hv[4];
      float hf[4];
      #pragma unroll
      for (int j = 0; j < 4; j++) {
        float zi = acc[j][0] + bias[j][0];
        float zf = acc[j][1] + bias[j][1];
        float zg = acc[j][2] + bias[j][2];
        float zo = acc[j][3] + bias[j][3];
        float cc = sigf(zf) * c1[j] + sigf(zi) * tanhfast(zg);
        c1[j] = cc;
        hf[j] = sigf(zo) * tanhfast(cc);
        hv[j] = (_Float16)hf[j];
      }
      #pragma unroll
      for (int j = 0; j < 4; j++)
        sm[mcol * LDS_STRIDE + 128 + wv * 16 + j * 4 + q] = hv[j];
      if (t == 999) {
        #pragma unroll
        for (int j = 0; j < 4; j++)
          h1l[((size_t)(g * 16 + mcol) << 7) + wv * 16 + j * 4 + q] = hf[j];
      }
      if ((t & 15) == 15 && tidx == 0)
        __hip_atomic_store(cons, t + 1, __ATOMIC_RELEASE, __HIP_MEMORY_SCOPE_AGENT);
      __syncthreads();
    }
  }
}

// =======================================================================
extern "C" void kernel_launch(void* const* d_in, const int* in_sizes, int n_in,
                              void* d_out, int out_size, void* d_ws, size_t ws_size,
                              hipStream_t stream) {
  const float* xs   = (const float*)d_in[0];
  const float* xtc  = (const float*)d_in[1];
  const float* Wgcn = (const float*)d_in[2];
  const float* bgcn = (const float*)d_in[3];
  const float* Wte  = (const float*)d_in[4];
  const float* bte  = (const float*)d_in[5];
  const float* Wih0 = (const float*)d_in[6];
  const float* Whh0 = (const float*)d_in[7];
  const float* bih0 = (const float*)d_in[8];
  const float* bhh0 = (const float*)d_in[9];
  const float* Wih1 = (const float*)d_in[10];
  const float* Whh1 = (const float*)d_in[11];
  const float* bih1 = (const float*)d_in[12];
  const float* bhh1 = (const float*)d_in[13];
  const float* W1   = (const float*)d_in[14];
  const float* b1   = (const float*)d_in[15];
  const float* W2   = (const float*)d_in[16];
  const float* b2   = (const float*)d_in[17];
  const float* W3   = (const float*)d_in[18];
  const float* b3   = (const float*)d_in[19];

  char* ws = (char*)d_ws;

  if (ws_size >= WS2_NEED) {
    _Float16* w0h  = (_Float16*)(ws + O2_W0H);
    _Float16* w1s  = (_Float16*)(ws + O2_W1);
    _Float16* wxs  = (_Float16*)(ws + O2_WX);
    float* bias0   = (float*)(ws + O2_B0);
    float* bias1   = (float*)(ws + O2_B1);
    float* peg     = (float*)(ws + O2_PE);
    float* h1l     = (float*)(ws + O2_H1);
    _Float16* zxo  = (_Float16*)(ws + O2_ZX);

    hipLaunchKernelGGL(k_bias, dim3(1), dim3(512), 0, stream, bih0, bhh0, bgcn, bte, Wih0, bih1, bhh1, bias0, bias1);
    hipLaunchKernelGGL(k_pe, dim3(2000), dim3(256), 0, stream, Wih0, bias0, peg);
    hipLaunchKernelGGL(k_wswz0b, dim3(256), dim3(256), 0, stream, Whh0, w0h);
    hipLaunchKernelGGL(k_wswz1, dim3(512), dim3(256), 0, stream, Wih1, Whh1, w1s);
    hipLaunchKernelGGL(k_wswzx, dim3(128), dim3(256), 0, stream, Wgcn, Wte, Wih0, wxs);
    hipLaunchKernelGGL(k_zx, dim3(1000), dim3(256), 0, stream, xs, xtc, wxs, peg, zxo);
    hipLaunchKernelGGL(k_lstm2, dim3(32), dim3(512), 0, stream, zxo, w0h, w1s, bias1, h1l);
    hipLaunchKernelGGL(k_mlp, dim3(512), dim3(128), 0, stream, h1l, W1, b1, W2, b2, W3, b3, (float*)d_out);
    return;
  }

  if (ws_size < WS_NEED) return;
  _Float16* w0   = (_Float16*)(ws + O_W0);
  _Float16* w1   = (_Float16*)(ws + O_W1);
  float* bias0   = (float*)(ws + O_B0);
  float* bias1   = (float*)(ws + O_B1);
  float* peg     = (float*)(ws + O_PE);
  _Float16* ring = (_Float16*)(ws + O_RING);
  float* h1l     = (float*)(ws + O_H1);
  int* cnt       = (int*)(ws + O_CNT);

  hipMemsetAsync(ws + O_CNT, 0, 16384, stream);
  hipLaunchKernelGGL(k_wswz0, dim3(384), dim3(256), 0, stream, Wgcn, Wte, Wih0, Whh0, w0);
  hipLaunchKernelGGL(k_wswz1, dim3(512), dim3(256), 0, stream, Wih1, Whh1, w1);
  hipLaunchKernelGGL(k_bias, dim3(1), dim3(512), 0, stream, bih0, bhh0, bgcn, bte, Wih0, bih1, bhh1, bias0, bias1);
  hipLaunchKernelGGL(k_pe, dim3(2000), dim3(256), 0, stream, Wih0, bias0, peg);
  hipLaunchKernelGGL(k_lstm, dim3(64), dim3(512), 0, stream, xs, xtc, w0, w1, peg, bias1, ring, cnt, h1l);
  hipLaunchKernelGGL(k_mlp, dim3(512), dim3(128), 0, stream, h1l, W1, b1, W2, b2, W3, b3, (float*)d_out);
}

// Round 3
// 7880.708 us; speedup vs baseline: 1.3790x; 1.3789x over previous
//
#include <hip/hip_runtime.h>

typedef _Float16 h8 __attribute__((ext_vector_type(8)));
typedef _Float16 h4v __attribute__((ext_vector_type(4)));
typedef float f4 __attribute__((ext_vector_type(4)));

// LDS batch-row: [x_eff 64 | h0 128 | h1 128] halfs + pad -> 328 halfs = 656 B
// 656/4 = 164 ≡ 4 (mod 32) -> worst 2-way bank alias (free); 656 % 16 == 0 (b128 ok)
#define SROW 328

// workspace layout (bytes) — total < 3 MB (well under the known-available 11 MB)
constexpr size_t O_W0 = 0;            // layer0 A-frags [wv8][j4][ks6][lane64][8h] = 196608 B
constexpr size_t O_W1 = 196608;       // layer1 A-frags [wv8][j4][ks8][lane64][8h] = 262144 B
constexpr size_t O_B0 = 458752;       // bias0_eff[512] f32 (permuted p = dim*4+gate)
constexpr size_t O_B1 = 460800;       // bias1[512] f32 (same permutation)
constexpr size_t O_PE = 462848;       // peg[1000][512] f32 (pe + bias0 folded)
constexpr size_t O_H1 = 2510848;      // h1_last[512][128] f32
constexpr size_t WS_NEED = 2772992;

__device__ __forceinline__ float sigf(float x) { return 1.0f / (1.0f + __expf(-x)); }
__device__ __forceinline__ float tanhfast(float x) {
  float e = __expf(2.0f * x);
  return 1.0f - 2.0f / (e + 1.0f);
}
// barrier draining LDS only — keeps global prefetch (vmcnt) in flight
__device__ __forceinline__ void bar_lds() {
  asm volatile("s_waitcnt lgkmcnt(0)\n\ts_barrier" ::: "memory");
}

// gate-slot permutation: slot s = wv*64 + j*16 + m, m = q*4 + reg
//   dim(s) = wv*16 + q*4 + j, gate(s) = reg  ->  orig row = reg*128 + dim
// so for A-frag (wv,j), tile-row m: row = (m&3)*128 + wv*16 + (m>>2)*4 + j
// bias/pe arrays indexed p = dim*4 + gate -> row = (p&3)*128 + (p>>2)

// ---- layer0 combined [x_eff(64) | Whh0(128)] A-fragments ----
__global__ void k_wswz0n(const float* __restrict__ Wgcn, const float* __restrict__ Wte,
                         const float* __restrict__ Wih0, const float* __restrict__ Whh0,
                         _Float16* __restrict__ out) {
  int tid = blockIdx.x * 256 + threadIdx.x;   // < 98304
  int e = tid & 7, lane = (tid >> 3) & 63;
  int fi = tid >> 9;                          // 0..191
  int ks = fi % 6; fi /= 6;
  int j = fi & 3, wv = fi >> 2;
  int m = lane & 15;
  int k = ks * 32 + (lane >> 4) * 8 + e;      // 0..191
  int row = (m & 3) * 128 + wv * 16 + (m >> 2) * 4 + j;
  float v = 0.f;
  if (k < 16) {                               // student, GCN-folded
    float s = 0.f;
    for (int dd = 0; dd < 64; dd++)
      s += Wgcn[k * 64 + dd] * (Wih0[row * 208 + dd] + Wih0[row * 208 + 64 + dd]);
    v = 0.5f * s;
  } else if (k < 42) {                        // teacher, folded through W_te
    float s = 0.f;
    for (int dd = 0; dd < 64; dd++)
      s += Wte[(k - 16) * 64 + dd] * Wih0[row * 208 + 144 + dd];
    v = s;
  } else if (k < 64) {
    v = 0.f;                                  // pad
  } else {
    v = Whh0[row * 128 + (k - 64)];
  }
  out[tid] = (_Float16)v;
}

// ---- layer1 [Wih1 | Whh1] A-fragments ----
__global__ void k_wswz1n(const float* __restrict__ Wih1, const float* __restrict__ Whh1,
                         _Float16* __restrict__ out) {
  int tid = blockIdx.x * 256 + threadIdx.x;   // < 131072
  int e = tid & 7, lane = (tid >> 3) & 63;
  int fi = tid >> 9;                          // 0..255
  int ks = fi & 7, j = (fi >> 3) & 3, wv = fi >> 5;
  int m = lane & 15;
  int k = ks * 32 + (lane >> 4) * 8 + e;      // 0..255
  int row = (m & 3) * 128 + wv * 16 + (m >> 2) * 4 + j;
  float v = (k < 128) ? Wih1[row * 128 + k] : Whh1[row * 128 + (k - 128)];
  out[tid] = (_Float16)v;
}

__global__ void k_bias(const float* __restrict__ bih0, const float* __restrict__ bhh0,
                       const float* __restrict__ bgcn, const float* __restrict__ bte,
                       const float* __restrict__ Wih0,
                       const float* __restrict__ bih1, const float* __restrict__ bhh1,
                       float* __restrict__ bias0, float* __restrict__ bias1) {
  int p = threadIdx.x;                        // 512
  int row = (p & 3) * 128 + (p >> 2);
  float s = bih0[row] + bhh0[row];
  for (int dd = 0; dd < 64; dd++)
    s += bgcn[dd] * (Wih0[row * 208 + dd] + Wih0[row * 208 + 64 + dd]);
  for (int dd = 0; dd < 64; dd++)
    s += bte[dd] * Wih0[row * 208 + 144 + dd];
  bias0[p] = s;
  bias1[p] = bih1[row] + bhh1[row];
}

__global__ void k_pe(const float* __restrict__ Wih0, const float* __restrict__ bias0,
                     float* __restrict__ peg) {
  int tid = blockIdx.x * 256 + threadIdx.x;   // < 512000
  int t = tid >> 9, p = tid & 511;
  int row = (p & 3) * 128 + (p >> 2);
  float acc = bias0[p];
  float tf = (float)t;
  #pragma unroll
  for (int i = 0; i < 8; i++) {
    float div = expf(-1.1512925464970228f * (float)i);  // exp(2i * -ln(10000)/16)
    float ang = tf * div;
    acc += sinf(ang) * Wih0[row * 208 + 128 + 2 * i]
         + cosf(ang) * Wih0[row * 208 + 129 + 2 * i];
  }
  peg[tid] = acc;
}

// ---- fused 2-layer LSTM: 32 blocks (1 per batch-group of 16), 512 thr, 1 block/CU ----
__global__ __launch_bounds__(512, 2) void k_lstm3(
    const float* __restrict__ xs, const float* __restrict__ xtc,
    const _Float16* __restrict__ w0s, const _Float16* __restrict__ w1s,
    const float* __restrict__ peg, const float* __restrict__ b1g,
    float* __restrict__ h1l) {
  __shared__ __align__(16) _Float16 sm[16 * SROW];
  const int tidx = threadIdx.x, lane = tidx & 63, wv = tidx >> 6;
  const int q = lane >> 4, mcol = lane & 15;
  const int g = blockIdx.x;

  for (int i = tidx; i < 16 * SROW; i += 512) sm[i] = (_Float16)0.f;

  // weights -> registers (A-fragments; expect AGPR allocation for most)
  h8 wf0[4][6];
  #pragma unroll
  for (int j = 0; j < 4; j++)
    #pragma unroll
    for (int ks = 0; ks < 6; ks++)
      wf0[j][ks] = ((const h8*)w0s)[((wv * 4 + j) * 6 + ks) * 64 + lane];
  h8 wf1[4][8];
  #pragma unroll
  for (int j = 0; j < 4; j++)
    #pragma unroll
    for (int ks = 0; ks < 8; ks++)
      wf1[j][ks] = ((const h8*)w1s)[((wv * 4 + j) * 8 + ks) * 64 + lane];
  f4 b1r[4];
  #pragma unroll
  for (int j = 0; j < 4; j++)
    b1r[j] = *(const f4*)(b1g + wv * 64 + q * 16 + j * 4);

  float c0[4] = {0.f, 0.f, 0.f, 0.f};
  float c1[4] = {0.f, 0.f, 0.f, 0.f};
  h8 h0f[4];
  #pragma unroll
  for (int i = 0; i < 4; i++) h0f[i] = (h8)(_Float16)0.f;
  const f4 z4 = {0.f, 0.f, 0.f, 0.f};

  // x staging roles (wave-0 = student; waves 1-3 + 16 lanes of wave 4 = teacher)
  const bool isA = tidx < 64;
  const int sa_row = tidx >> 2, sa_c = (tidx & 3) * 4;
  const bool isB = (tidx >= 64) && (tidx < 272);
  const int t2 = tidx - 64;
  const int tb_row = t2 / 13, tb_c = (t2 - tb_row * 13) * 2;

  f4 sA = z4, sB = z4;
  float2 tv = {0.f, 0.f};
  if (isA) {
    const float* xb = xs + ((size_t)(g * 16 + sa_row) * 1000 + 0) * 32;
    sA = *(const f4*)(xb + sa_c);
    sB = *(const f4*)(xb + 16 + sa_c);
  }
  if (isB) tv = *(const float2*)(xtc + ((size_t)(g * 16 + tb_row) * 1000 + 0) * 26 + tb_c);
  if (isA) {
    h4v o = {(_Float16)(sA[0] + sB[0]), (_Float16)(sA[1] + sB[1]),
             (_Float16)(sA[2] + sB[2]), (_Float16)(sA[3] + sB[3])};
    *(h4v*)(sm + sa_row * SROW + sa_c) = o;
  }
  if (isB) {
    sm[tb_row * SROW + 16 + tb_c] = (_Float16)tv.x;
    sm[tb_row * SROW + 16 + tb_c + 1] = (_Float16)tv.y;
  }
  __syncthreads();

  #pragma unroll 1
  for (int t = 0; t < 1000; t++) {
    // --- early: global prefetch x(t+1), pe(t); LDS reads of x(t), h1(t-1) ---
    const int tn = (t < 999) ? t + 1 : 999;
    if (isA) {
      const float* xb = xs + ((size_t)(g * 16 + sa_row) * 1000 + tn) * 32;
      sA = *(const f4*)(xb + sa_c);
      sB = *(const f4*)(xb + 16 + sa_c);
    }
    if (isB) tv = *(const float2*)(xtc + ((size_t)(g * 16 + tb_row) * 1000 + tn) * 26 + tb_c);
    f4 pe[4];
    #pragma unroll
    for (int j = 0; j < 4; j++)
      pe[j] = *(const f4*)(peg + (size_t)t * 512 + wv * 64 + q * 16 + j * 4);
    h8 h1f[4], xf[2];
    #pragma unroll
    for (int i = 0; i < 4; i++)
      h1f[i] = *(const h8*)(sm + mcol * SROW + 192 + i * 32 + q * 8);
    #pragma unroll
    for (int i = 0; i < 2; i++)
      xf[i] = *(const h8*)(sm + mcol * SROW + i * 32 + q * 8);

    // --- layer 0: z = Wx*x(t) + Whh0*h0(t-1) (+pe+b later) ---
    f4 acc[4] = {z4, z4, z4, z4};
    #pragma unroll
    for (int ks = 0; ks < 2; ks++)
      #pragma unroll
      for (int j = 0; j < 4; j++)
        acc[j] = __builtin_amdgcn_mfma_f32_16x16x32_f16(wf0[j][ks], xf[ks], acc[j], 0, 0, 0);
    #pragma unroll
    for (int ks = 0; ks < 4; ks++)
      #pragma unroll
      for (int j = 0; j < 4; j++)
        acc[j] = __builtin_amdgcn_mfma_f32_16x16x32_f16(wf0[j][2 + ks], h0f[ks], acc[j], 0, 0, 0);

    h4v hv0;
    #pragma unroll
    for (int j = 0; j < 4; j++) {
      float zi = acc[j][0] + pe[j][0];
      float zf = acc[j][1] + pe[j][1];
      float zg = acc[j][2] + pe[j][2];
      float zo = acc[j][3] + pe[j][3];
      float cc = sigf(zf) * c0[j] + sigf(zi) * tanhfast(zg);
      c0[j] = cc;
      hv0[j] = (_Float16)(sigf(zo) * tanhfast(cc));
    }
    // write h0(t): lane's 4 dims are contiguous -> one b64
    *(h4v*)(sm + mcol * SROW + 64 + wv * 16 + q * 4) = hv0;
    bar_lds();   // B: h0(t) visible; x(t)/h1(t-1) reads done

    // read h0(t) frags once: used by layer1(t) AND layer0(t+1)
    #pragma unroll
    for (int i = 0; i < 4; i++)
      h0f[i] = *(const h8*)(sm + mcol * SROW + 64 + i * 32 + q * 8);
    // stage x(t+1) (x(t) reads completed before B)
    if (isA) {
      h4v o = {(_Float16)(sA[0] + sB[0]), (_Float16)(sA[1] + sB[1]),
               (_Float16)(sA[2] + sB[2]), (_Float16)(sA[3] + sB[3])};
      *(h4v*)(sm + sa_row * SROW + sa_c) = o;
    }
    if (isB) {
      sm[tb_row * SROW + 16 + tb_c] = (_Float16)tv.x;
      sm[tb_row * SROW + 16 + tb_c + 1] = (_Float16)tv.y;
    }

    // --- layer 1: z = Wih1*h0(t) + Whh1*h1(t-1) + b1 (acc-init) ---
    f4 a1[4] = {b1r[0], b1r[1], b1r[2], b1r[3]};
    #pragma unroll
    for (int ks = 0; ks < 4; ks++)            // h1 part first (frags already in regs)
      #pragma unroll
      for (int j = 0; j < 4; j++)
        a1[j] = __builtin_amdgcn_mfma_f32_16x16x32_f16(wf1[j][4 + ks], h1f[ks], a1[j], 0, 0, 0);
    #pragma unroll
    for (int ks = 0; ks < 4; ks++)
      #pragma unroll
      for (int j = 0; j < 4; j++)
        a1[j] = __builtin_amdgcn_mfma_f32_16x16x32_f16(wf1[j][ks], h0f[ks], a1[j], 0, 0, 0);

    h4v hv1; f4 hfv;
    #pragma unroll
    for (int j = 0; j < 4; j++) {
      float zi = a1[j][0];
      float zf = a1[j][1];
      float zg = a1[j][2];
      float zo = a1[j][3];
      float cc = sigf(zf) * c1[j] + sigf(zi) * tanhfast(zg);
      c1[j] = cc;
      float h = sigf(zo) * tanhfast(cc);
      hfv[j] = h;
      hv1[j] = (_Float16)h;
    }
    *(h4v*)(sm + mcol * SROW + 192 + wv * 16 + q * 4) = hv1;
    if (t == 999)
      *(f4*)(h1l + (size_t)(g * 16 + mcol) * 128 + wv * 16 + q * 4) = hfv;
    bar_lds();   // C: h1(t), x(t+1) visible for next step
  }
}

// ---- MLP head: one block per batch row ----
__global__ void k_mlp(const float* __restrict__ h1l,
                      const float* __restrict__ W1, const float* __restrict__ b1,
                      const float* __restrict__ W2, const float* __restrict__ b2,
                      const float* __restrict__ W3, const float* __restrict__ b3,
                      float* __restrict__ out) {
  __shared__ float sh[128];
  __shared__ float sy1[128];
  __shared__ float sy2[64];
  const int b = blockIdx.x;
  const int t = threadIdx.x;   // 128 threads
  sh[t] = h1l[b * 128 + t];
  __syncthreads();
  {
    float s = b1[t];
    const float* wr = W1 + t * 128;
    for (int k = 0; k < 128; k++) s += sh[k] * wr[k];
    sy1[t] = fmaxf(s, 0.f);
  }
  __syncthreads();
  if (t < 64) {
    float s = b2[t];
    const float* wr = W2 + t * 128;
    for (int k = 0; k < 128; k++) s += sy1[k] * wr[k];
    sy2[t] = fmaxf(s, 0.f);
  }
  __syncthreads();
  if (t < 26) {
    float s = b3[t];
    const float* wr = W3 + t * 64;
    for (int k = 0; k < 64; k++) s += sy2[k] * wr[k];
    out[b * 26 + t] = s;
  }
}

extern "C" void kernel_launch(void* const* d_in, const int* in_sizes, int n_in,
                              void* d_out, int out_size, void* d_ws, size_t ws_size,
                              hipStream_t stream) {
  const float* xs   = (const float*)d_in[0];
  const float* xtc  = (const float*)d_in[1];
  const float* Wgcn = (const float*)d_in[2];
  const float* bgcn = (const float*)d_in[3];
  const float* Wte  = (const float*)d_in[4];
  const float* bte  = (const float*)d_in[5];
  const float* Wih0 = (const float*)d_in[6];
  const float* Whh0 = (const float*)d_in[7];
  const float* bih0 = (const float*)d_in[8];
  const float* bhh0 = (const float*)d_in[9];
  const float* Wih1 = (const float*)d_in[10];
  const float* Whh1 = (const float*)d_in[11];
  const float* bih1 = (const float*)d_in[12];
  const float* bhh1 = (const float*)d_in[13];
  const float* W1   = (const float*)d_in[14];
  const float* b1   = (const float*)d_in[15];
  const float* W2   = (const float*)d_in[16];
  const float* b2   = (const float*)d_in[17];
  const float* W3   = (const float*)d_in[18];
  const float* b3   = (const float*)d_in[19];

  char* ws = (char*)d_ws;
  if (ws_size < WS_NEED) return;

  _Float16* w0s  = (_Float16*)(ws + O_W0);
  _Float16* w1s  = (_Float16*)(ws + O_W1);
  float* bias0   = (float*)(ws + O_B0);
  float* bias1   = (float*)(ws + O_B1);
  float* peg     = (float*)(ws + O_PE);
  float* h1l     = (float*)(ws + O_H1);

  hipLaunchKernelGGL(k_bias, dim3(1), dim3(512), 0, stream, bih0, bhh0, bgcn, bte, Wih0, bih1, bhh1, bias0, bias1);
  hipLaunchKernelGGL(k_pe, dim3(2000), dim3(256), 0, stream, Wih0, bias0, peg);
  hipLaunchKernelGGL(k_wswz0n, dim3(384), dim3(256), 0, stream, Wgcn, Wte, Wih0, Whh0, w0s);
  hipLaunchKernelGGL(k_wswz1n, dim3(512), dim3(256), 0, stream, Wih1, Whh1, w1s);
  hipLaunchKernelGGL(k_lstm3, dim3(32), dim3(512), 0, stream, xs, xtc, w0s, w1s, peg, bias1, h1l);
  hipLaunchKernelGGL(k_mlp, dim3(512), dim3(128), 0, stream, h1l, W1, b1, W2, b2, W3, b3, (float*)d_out);
}

// Round 4
// 4325.833 us; speedup vs baseline: 2.5122x; 1.8218x over previous
//
#include <hip/hip_runtime.h>

typedef _Float16 h8 __attribute__((ext_vector_type(8)));
typedef _Float16 h4v __attribute__((ext_vector_type(4)));
typedef float f4 __attribute__((ext_vector_type(4)));

// LDS map (halfs): [0,65536) layer1-Wih1 frags; [65536,72832) staging 16 rows x SROW;
// [72832,73856) b1 as 512 f32.  Total 147712 B (<160 KB -> 1 block/CU).
#define SROW 456     // staging row: x[0,64) | h0[64,192) | h1a[192,320) | h1b[320,448) | pad
#define STG0 65536
#define B1OFF 72832

// workspace layout (bytes)
constexpr size_t O_W0 = 0;            // layer0 A-frags [wv8][j4][ks6][lane64][8h] = 196608 B
constexpr size_t O_W1 = 196608;       // layer1: [LDS part 65536h][reg part 65536h] = 262144 B
constexpr size_t O_B0 = 458752;       // bias0_eff[512] f32 (p = dim*4+gate)
constexpr size_t O_B1 = 460800;       // bias1[512] f32
constexpr size_t O_PE = 462848;       // peg[1000][512] f32 (pe + bias0 folded)
constexpr size_t O_H1 = 2510848;      // h1_last[512][128] f32
constexpr size_t WS_NEED = 2772992;

__device__ __forceinline__ float sigf(float x) { return 1.0f / (1.0f + __expf(-x)); }
__device__ __forceinline__ float tanhfast(float x) {
  float e = __expf(2.0f * x);
  return 1.0f - 2.0f / (e + 1.0f);
}
// barrier draining LDS only — global prefetch (vmcnt) stays in flight
__device__ __forceinline__ void bar_lds() {
  asm volatile("s_waitcnt lgkmcnt(0)\n\ts_barrier" ::: "memory");
}

// gate-slot permutation: A-frag (wv,j), tile-row m: row = (m&3)*128 + wv*16 + (m>>2)*4 + j
// bias/pe arrays indexed p = dim*4 + gate -> row = (p&3)*128 + (p>>2)

// ---- layer0 combined [x_eff(64) | Whh0(128)] A-fragments ----
__global__ void k_wswz0n(const float* __restrict__ Wgcn, const float* __restrict__ Wte,
                         const float* __restrict__ Wih0, const float* __restrict__ Whh0,
                         _Float16* __restrict__ out) {
  int tid = blockIdx.x * 256 + threadIdx.x;   // < 98304
  int e = tid & 7, lane = (tid >> 3) & 63;
  int fi = tid >> 9;                          // 0..191
  int ks = fi % 6; fi /= 6;
  int j = fi & 3, wv = fi >> 2;
  int m = lane & 15;
  int k = ks * 32 + (lane >> 4) * 8 + e;      // 0..191
  int row = (m & 3) * 128 + wv * 16 + (m >> 2) * 4 + j;
  float v = 0.f;
  if (k < 16) {                               // student, GCN-folded (0.5 factor inside)
    float s = 0.f;
    for (int dd = 0; dd < 64; dd++)
      s += Wgcn[k * 64 + dd] * (Wih0[row * 208 + dd] + Wih0[row * 208 + 64 + dd]);
    v = 0.5f * s;
  } else if (k < 42) {                        // teacher, folded through W_te
    float s = 0.f;
    for (int dd = 0; dd < 64; dd++)
      s += Wte[(k - 16) * 64 + dd] * Wih0[row * 208 + 144 + dd];
    v = s;
  } else if (k < 64) {
    v = 0.f;                                  // pad
  } else {
    v = Whh0[row * 128 + (k - 64)];
  }
  out[tid] = (_Float16)v;
}

// ---- layer1 [Wih1 | Whh1] A-fragments, split: ks0..3 (Wih1) -> LDS image, ks4..7 -> regs ----
__global__ void k_wswz1n(const float* __restrict__ Wih1, const float* __restrict__ Whh1,
                         _Float16* __restrict__ out) {
  int tid = blockIdx.x * 256 + threadIdx.x;   // < 131072
  int e = tid & 7, lane = (tid >> 3) & 63;
  int fi = tid >> 9;                          // 0..255
  int ks = fi & 7, j = (fi >> 3) & 3, wv = fi >> 5;
  int m = lane & 15;
  int k = ks * 32 + (lane >> 4) * 8 + e;      // 0..255
  int row = (m & 3) * 128 + wv * 16 + (m >> 2) * 4 + j;
  float v = (k < 128) ? Wih1[row * 128 + k] : Whh1[row * 128 + (k - 128)];
  size_t dst;
  if (ks < 4) dst = (((size_t)((wv * 4 + j) * 4 + ks) * 64 + lane) * 8 + e);
  else        dst = 65536 + (((size_t)((wv * 4 + j) * 4 + (ks - 4)) * 64 + lane) * 8 + e);
  out[dst] = (_Float16)v;
}

__global__ void k_bias(const float* __restrict__ bih0, const float* __restrict__ bhh0,
                       const float* __restrict__ bgcn, const float* __restrict__ bte,
                       const float* __restrict__ Wih0,
                       const float* __restrict__ bih1, const float* __restrict__ bhh1,
                       float* __restrict__ bias0, float* __restrict__ bias1) {
  int p = threadIdx.x;                        // 512
  int row = (p & 3) * 128 + (p >> 2);
  float s = bih0[row] + bhh0[row];
  for (int dd = 0; dd < 64; dd++)
    s += bgcn[dd] * (Wih0[row * 208 + dd] + Wih0[row * 208 + 64 + dd]);
  for (int dd = 0; dd < 64; dd++)
    s += bte[dd] * Wih0[row * 208 + 144 + dd];
  bias0[p] = s;
  bias1[p] = bih1[row] + bhh1[row];
}

__global__ void k_pe(const float* __restrict__ Wih0, const float* __restrict__ bias0,
                     float* __restrict__ peg) {
  int tid = blockIdx.x * 256 + threadIdx.x;   // < 512000
  int t = tid >> 9, p = tid & 511;
  int row = (p & 3) * 128 + (p >> 2);
  float acc = bias0[p];
  float tf = (float)t;
  #pragma unroll
  for (int i = 0; i < 8; i++) {
    float div = expf(-1.1512925464970228f * (float)i);  // exp(2i * -ln(10000)/16)
    float ang = tf * div;
    acc += sinf(ang) * Wih0[row * 208 + 128 + 2 * i]
         + cosf(ang) * Wih0[row * 208 + 129 + 2 * i];
  }
  peg[tid] = acc;
}

// ---- fused 2-layer LSTM, reg+LDS weight split: 32 blocks x 512 thr, 1 block/CU ----
__global__ __launch_bounds__(512, 2) void k_lstm4(
    const float* __restrict__ xs, const float* __restrict__ xtc,
    const _Float16* __restrict__ w0s, const _Float16* __restrict__ w1s,
    const float* __restrict__ peg, const float* __restrict__ b1g,
    float* __restrict__ h1l) {
  __shared__ __align__(16) _Float16 sm[73856];   // 147712 B
  const int tidx = threadIdx.x, lane = tidx & 63, wv = tidx >> 6;
  const int q = lane >> 4, mcol = lane & 15;
  const int g = blockIdx.x;

  // ---- init: Wih1 frags -> LDS (layout identical to global image) ----
  {
    const h8* src = (const h8*)w1s;
    h8* dst = (h8*)sm;
    for (int i = tidx; i < 8192; i += 512) dst[i] = src[i];
  }
  for (int i = tidx; i < 7296; i += 512) sm[STG0 + i] = (_Float16)0.f;
  float* bsm = (float*)(sm + B1OFF);
  bsm[tidx] = b1g[tidx];

  // ---- reg weights: layer0 full (96 regs) + layer1 Whh1 part (64 regs) ----
  h8 wf0[4][6];
  #pragma unroll
  for (int j = 0; j < 4; j++)
    #pragma unroll
    for (int ks = 0; ks < 6; ks++)
      wf0[j][ks] = ((const h8*)w0s)[((wv * 4 + j) * 6 + ks) * 64 + lane];
  h8 wf1h[4][4];
  #pragma unroll
  for (int j = 0; j < 4; j++)
    #pragma unroll
    for (int ks = 0; ks < 4; ks++)
      wf1h[j][ks] = ((const h8*)(w1s + 65536))[((wv * 4 + j) * 4 + ks) * 64 + lane];

  float c0[4] = {0.f, 0.f, 0.f, 0.f};
  float c1[4] = {0.f, 0.f, 0.f, 0.f};
  h8 h0f[4];
  #pragma unroll
  for (int i = 0; i < 4; i++) h0f[i] = (h8)(_Float16)0.f;

  _Float16* srow_m = sm + STG0 + mcol * SROW;           // this lane's B-frag row
  const _Float16* wth = sm + wv * 8192 + lane * 8;      // this lane's Wih1 frag base

  // x staging roles: wave0 lanes = student (16B each); tidx 64..271 = teacher (2 vals each)
  const bool isA = tidx < 64;
  const int sa_row = tidx >> 2, sa_c = (tidx & 3) * 4;
  const bool isB = (tidx >= 64) && (tidx < 272);
  const int t2 = tidx - 64;
  const int tb_row = t2 / 13, tb_c = (t2 - tb_row * 13) * 2;
  _Float16* arow = sm + STG0 + sa_row * SROW;
  _Float16* brow = sm + STG0 + tb_row * SROW;

  h4v xe = {(_Float16)0.f, (_Float16)0.f, (_Float16)0.f, (_Float16)0.f};
  _Float16 te0 = (_Float16)0.f, te1 = (_Float16)0.f;
  // stage x(0) -> LDS, x(1) -> regs
  if (isA) {
    const float* xb = xs + ((size_t)(g * 16 + sa_row) * 1000 + 0) * 32;
    f4 a = *(const f4*)(xb + sa_c), b = *(const f4*)(xb + 16 + sa_c);
    h4v o = {(_Float16)(a[0] + b[0]), (_Float16)(a[1] + b[1]),
             (_Float16)(a[2] + b[2]), (_Float16)(a[3] + b[3])};
    *(h4v*)(arow + sa_c) = o;
    const float* xb1 = xs + ((size_t)(g * 16 + sa_row) * 1000 + 1) * 32;
    f4 a1v = *(const f4*)(xb1 + sa_c), b1v = *(const f4*)(xb1 + 16 + sa_c);
    xe[0] = (_Float16)(a1v[0] + b1v[0]); xe[1] = (_Float16)(a1v[1] + b1v[1]);
    xe[2] = (_Float16)(a1v[2] + b1v[2]); xe[3] = (_Float16)(a1v[3] + b1v[3]);
  }
  if (isB) {
    float2 tv = *(const float2*)(xtc + ((size_t)(g * 16 + tb_row) * 1000 + 0) * 26 + tb_c);
    brow[16 + tb_c] = (_Float16)tv.x; brow[16 + tb_c + 1] = (_Float16)tv.y;
    float2 tv1 = *(const float2*)(xtc + ((size_t)(g * 16 + tb_row) * 1000 + 1) * 26 + tb_c);
    te0 = (_Float16)tv1.x; te1 = (_Float16)tv1.y;
  }
  __syncthreads();

  #pragma unroll 1
  for (int t = 0; t < 1000; t++) {
    // issue global prefetch for x(t+2) (consumed at end of this step)
    const int tn = (t < 998) ? t + 2 : 999;
    f4 sA = {0.f, 0.f, 0.f, 0.f}, sB = {0.f, 0.f, 0.f, 0.f};
    float2 tvr = {0.f, 0.f};
    if (isA) {
      const float* xb = xs + ((size_t)(g * 16 + sa_row) * 1000 + tn) * 32;
      sA = *(const f4*)(xb + sa_c); sB = *(const f4*)(xb + 16 + sa_c);
    }
    if (isB) tvr = *(const float2*)(xtc + ((size_t)(g * 16 + tb_row) * 1000 + tn) * 26 + tb_c);

    // ---- layer 0: acc starts as pe(t)+bias0, accumulate Wx*x(t) + Whh0*h0(t-1) ----
    f4 acc[4];
    #pragma unroll
    for (int j = 0; j < 4; j++)
      acc[j] = *(const f4*)(peg + (size_t)t * 512 + wv * 64 + q * 16 + j * 4);
    h8 xf0 = *(const h8*)(srow_m + q * 8);
    h8 xf1 = *(const h8*)(srow_m + 32 + q * 8);
    #pragma unroll
    for (int j = 0; j < 4; j++)
      acc[j] = __builtin_amdgcn_mfma_f32_16x16x32_f16(wf0[j][0], xf0, acc[j], 0, 0, 0);
    #pragma unroll
    for (int j = 0; j < 4; j++)
      acc[j] = __builtin_amdgcn_mfma_f32_16x16x32_f16(wf0[j][1], xf1, acc[j], 0, 0, 0);
    #pragma unroll
    for (int ks = 0; ks < 4; ks++)
      #pragma unroll
      for (int j = 0; j < 4; j++)
        acc[j] = __builtin_amdgcn_mfma_f32_16x16x32_f16(wf0[j][2 + ks], h0f[ks], acc[j], 0, 0, 0);

    h4v hv0;
    #pragma unroll
    for (int j = 0; j < 4; j++) {
      float cc = sigf(acc[j][1]) * c0[j] + sigf(acc[j][0]) * tanhfast(acc[j][2]);
      c0[j] = cc;
      hv0[j] = (_Float16)(sigf(acc[j][3]) * tanhfast(cc));
    }
    *(h4v*)(srow_m + 64 + wv * 16 + q * 4) = hv0;   // h0(t), lane's 4 dims contiguous
    bar_lds();   // B: h0(t) visible; x(t)/h0(t-1) LDS reads done

    // ---- layer 1: a1 = b1 (LDS broadcast) + Whh1*h1(t-1) + Wih1*h0(t) ----
    h8 h1f[4];
    const int rb = 192 + (t & 1) * 128;             // h1 read slot (double-buffered)
    #pragma unroll
    for (int i = 0; i < 4; i++)
      h1f[i] = *(const h8*)(srow_m + rb + i * 32 + q * 8);
    f4 a1[4];
    #pragma unroll
    for (int j = 0; j < 4; j++)
      a1[j] = *(const f4*)(bsm + wv * 64 + q * 16 + j * 4);
    #pragma unroll
    for (int ks = 0; ks < 4; ks++)
      #pragma unroll
      for (int j = 0; j < 4; j++)
        a1[j] = __builtin_amdgcn_mfma_f32_16x16x32_f16(wf1h[j][ks], h1f[ks], a1[j], 0, 0, 0);
    #pragma unroll
    for (int i = 0; i < 4; i++)
      h0f[i] = *(const h8*)(srow_m + 64 + i * 32 + q * 8);   // reused at t+1 layer0
    // stage x(t+1) from regs (no vmcnt dependence)
    if (isA) *(h4v*)(arow + sa_c) = xe;
    if (isB) { brow[16 + tb_c] = te0; brow[16 + tb_c + 1] = te1; }
    #pragma unroll
    for (int ks = 0; ks < 4; ks++) {
      #pragma unroll
      for (int j = 0; j < 4; j++) {
        h8 wl = *(const h8*)(wth + (j * 4 + ks) * 512);      // Wih1 frag from LDS
        a1[j] = __builtin_amdgcn_mfma_f32_16x16x32_f16(wl, h0f[ks], a1[j], 0, 0, 0);
      }
    }

    h4v hv1; f4 hfv;
    #pragma unroll
    for (int j = 0; j < 4; j++) {
      float cc = sigf(a1[j][1]) * c1[j] + sigf(a1[j][0]) * tanhfast(a1[j][2]);
      c1[j] = cc;
      float h = sigf(a1[j][3]) * tanhfast(cc);
      hfv[j] = h;
      hv1[j] = (_Float16)h;
    }
    *(h4v*)(srow_m + 192 + ((t + 1) & 1) * 128 + wv * 16 + q * 4) = hv1;  // write slot
    if (t == 999)
      *(f4*)(h1l + (size_t)(g * 16 + mcol) * 128 + wv * 16 + q * 4) = hfv;

    // consume prefetched x(t+2) -> regs (waitcnt lands here, a full step after issue)
    if (isA) {
      xe[0] = (_Float16)(sA[0] + sB[0]); xe[1] = (_Float16)(sA[1] + sB[1]);
      xe[2] = (_Float16)(sA[2] + sB[2]); xe[3] = (_Float16)(sA[3] + sB[3]);
    }
    if (isB) { te0 = (_Float16)tvr.x; te1 = (_Float16)tvr.y; }
    bar_lds();   // C: h1(t), x(t+1) visible for next step
  }
}

// ---- MLP head: one block per batch row ----
__global__ void k_mlp(const float* __restrict__ h1l,
                      const float* __restrict__ W1, const float* __restrict__ b1,
                      const float* __restrict__ W2, const float* __restrict__ b2,
                      const float* __restrict__ W3, const float* __restrict__ b3,
                      float* __restrict__ out) {
  __shared__ float sh[128];
  __shared__ float sy1[128];
  __shared__ float sy2[64];
  const int b = blockIdx.x;
  const int t = threadIdx.x;   // 128 threads
  sh[t] = h1l[b * 128 + t];
  __syncthreads();
  {
    float s = b1[t];
    const float* wr = W1 + t * 128;
    for (int k = 0; k < 128; k++) s += sh[k] * wr[k];
    sy1[t] = fmaxf(s, 0.f);
  }
  __syncthreads();
  if (t < 64) {
    float s = b2[t];
    const float* wr = W2 + t * 128;
    for (int k = 0; k < 128; k++) s += sy1[k] * wr[k];
    sy2[t] = fmaxf(s, 0.f);
  }
  __syncthreads();
  if (t < 26) {
    float s = b3[t];
    const float* wr = W3 + t * 64;
    for (int k = 0; k < 64; k++) s += sy2[k] * wr[k];
    out[b * 26 + t] = s;
  }
}

extern "C" void kernel_launch(void* const* d_in, const int* in_sizes, int n_in,
                              void* d_out, int out_size, void* d_ws, size_t ws_size,
                              hipStream_t stream) {
  const float* xs   = (const float*)d_in[0];
  const float* xtc  = (const float*)d_in[1];
  const float* Wgcn = (const float*)d_in[2];
  const float* bgcn = (const float*)d_in[3];
  const float* Wte  = (const float*)d_in[4];
  const float* bte  = (const float*)d_in[5];
  const float* Wih0 = (const float*)d_in[6];
  const float* Whh0 = (const float*)d_in[7];
  const float* bih0 = (const float*)d_in[8];
  const float* bhh0 = (const float*)d_in[9];
  const float* Wih1 = (const float*)d_in[10];
  const float* Whh1 = (const float*)d_in[11];
  const float* bih1 = (const float*)d_in[12];
  const float* bhh1 = (const float*)d_in[13];
  const float* W1   = (const float*)d_in[14];
  const float* b1   = (const float*)d_in[15];
  const float* W2   = (const float*)d_in[16];
  const float* b2   = (const float*)d_in[17];
  const float* W3   = (const float*)d_in[18];
  const float* b3   = (const float*)d_in[19];

  char* ws = (char*)d_ws;
  if (ws_size < WS_NEED) return;

  _Float16* w0s  = (_Float16*)(ws + O_W0);
  _Float16* w1s  = (_Float16*)(ws + O_W1);
  float* bias0   = (float*)(ws + O_B0);
  float* bias1   = (float*)(ws + O_B1);
  float* peg     = (float*)(ws + O_PE);
  float* h1l     = (float*)(ws + O_H1);

  hipLaunchKernelGGL(k_bias, dim3(1), dim3(512), 0, stream, bih0, bhh0, bgcn, bte, Wih0, bih1, bhh1, bias0, bias1);
  hipLaunchKernelGGL(k_pe, dim3(2000), dim3(256), 0, stream, Wih0, bias0, peg);
  hipLaunchKernelGGL(k_wswz0n, dim3(384), dim3(256), 0, stream, Wgcn, Wte, Wih0, Whh0, w0s);
  hipLaunchKernelGGL(k_wswz1n, dim3(512), dim3(256), 0, stream, Wih1, Whh1, w1s);
  hipLaunchKernelGGL(k_lstm4, dim3(32), dim3(512), 0, stream, xs, xtc, w0s, w1s, peg, bias1, h1l);
  hipLaunchKernelGGL(k_mlp, dim3(512), dim3(128), 0, stream, h1l, W1, b1, W2, b2, W3, b3, (float*)d_out);
}

// Round 5
// 2761.089 us; speedup vs baseline: 3.9358x; 1.5667x over previous
//
#include <hip/hip_runtime.h>

typedef _Float16 h8 __attribute__((ext_vector_type(8)));
typedef _Float16 h4v __attribute__((ext_vector_type(4)));
typedef float f4 __attribute__((ext_vector_type(4)));

// ---------------- workspace layout (bytes) ----------------
constexpr size_t O_W0   = 0;         // layer0 A-frags [wv8][j4][ks6][lane64][8h] = 196608 B
constexpr size_t O_W1   = 196608;    // layer1 A-frags [wv8][j4][ks8][lane64][8h] = 262144 B
constexpr size_t O_B0   = 458752;    // bias0_eff[512] f32 (p = dim*4+gate)
constexpr size_t O_B1   = 460800;    // bias1[512] f32
constexpr size_t O_PE   = 462848;    // peg[1000][512] f32 (pe + bias0 folded)
constexpr size_t O_H1   = 2510848;   // h1_last[512][128] f32
constexpr size_t O_RING = 2772992;   // h0 ring [32 g][32 slot][2048 halfs] = 4 MB
constexpr size_t O_CNT  = 6967296;   // flag[32] (stride 64 int) ; cons at +8192 B
constexpr size_t WS_NEED = 6983680;

// A-block LDS row: [x0 64 | x1 64 | h0a 128 | h0b 128 | pad 8] = 392 halfs
#define SROWA 392
// B-block LDS: chunk buf0 [0,16384), buf1 [16384,32768), h1 rows 16 x 264 at 32768
#define B_H1 32768

__device__ __forceinline__ float sigf(float x) { return 1.0f / (1.0f + __expf(-x)); }
__device__ __forceinline__ float tanhfast(float x) {
  float e = __expf(2.0f * x);
  return 1.0f - 2.0f / (e + 1.0f);
}
__device__ __forceinline__ void bar_lds() {
  asm volatile("s_waitcnt lgkmcnt(0)\n\ts_barrier" ::: "memory");
}
__device__ __forceinline__ void poll_ge(int* p, int target) {
  int gd = 0;
  while (__hip_atomic_load(p, __ATOMIC_RELAXED, __HIP_MEMORY_SCOPE_AGENT) < target) {
    __builtin_amdgcn_s_sleep(4);
    if (++gd > 30000000) break;
  }
}

// gate-slot permutation: A-frag (wv,j), tile-row m: row = (m&3)*128 + wv*16 + (m>>2)*4 + j
// bias/pe arrays indexed p = dim*4 + gate -> row = (p&3)*128 + (p>>2)

// ---- layer0 combined [x_eff(64) | Whh0(128)] A-fragments ----
__global__ void k_wswz0n(const float* __restrict__ Wgcn, const float* __restrict__ Wte,
                         const float* __restrict__ Wih0, const float* __restrict__ Whh0,
                         _Float16* __restrict__ out) {
  int tid = blockIdx.x * 256 + threadIdx.x;   // < 98304
  int e = tid & 7, lane = (tid >> 3) & 63;
  int fi = tid >> 9;                          // 0..191
  int ks = fi % 6; fi /= 6;
  int j = fi & 3, wv = fi >> 2;
  int m = lane & 15;
  int k = ks * 32 + (lane >> 4) * 8 + e;      // 0..191
  int row = (m & 3) * 128 + wv * 16 + (m >> 2) * 4 + j;
  float v = 0.f;
  if (k < 16) {
    float s = 0.f;
    for (int dd = 0; dd < 64; dd++)
      s += Wgcn[k * 64 + dd] * (Wih0[row * 208 + dd] + Wih0[row * 208 + 64 + dd]);
    v = 0.5f * s;
  } else if (k < 42) {
    float s = 0.f;
    for (int dd = 0; dd < 64; dd++)
      s += Wte[(k - 16) * 64 + dd] * Wih0[row * 208 + 144 + dd];
    v = s;
  } else if (k < 64) {
    v = 0.f;
  } else {
    v = Whh0[row * 128 + (k - 64)];
  }
  out[tid] = (_Float16)v;
}

// ---- layer1 [Wih1 | Whh1] A-fragments (full, all reg-resident in consumer) ----
__global__ void k_wswz1n(const float* __restrict__ Wih1, const float* __restrict__ Whh1,
                         _Float16* __restrict__ out) {
  int tid = blockIdx.x * 256 + threadIdx.x;   // < 131072
  int e = tid & 7, lane = (tid >> 3) & 63;
  int fi = tid >> 9;                          // 0..255
  int ks = fi & 7, j = (fi >> 3) & 3, wv = fi >> 5;
  int m = lane & 15;
  int k = ks * 32 + (lane >> 4) * 8 + e;      // 0..255
  int row = (m & 3) * 128 + wv * 16 + (m >> 2) * 4 + j;
  float v = (k < 128) ? Wih1[row * 128 + k] : Whh1[row * 128 + (k - 128)];
  out[tid] = (_Float16)v;
}

__global__ void k_bias(const float* __restrict__ bih0, const float* __restrict__ bhh0,
                       const float* __restrict__ bgcn, const float* __restrict__ bte,
                       const float* __restrict__ Wih0,
                       const float* __restrict__ bih1, const float* __restrict__ bhh1,
                       float* __restrict__ bias0, float* __restrict__ bias1) {
  int p = threadIdx.x;                        // 512
  int row = (p & 3) * 128 + (p >> 2);
  float s = bih0[row] + bhh0[row];
  for (int dd = 0; dd < 64; dd++)
    s += bgcn[dd] * (Wih0[row * 208 + dd] + Wih0[row * 208 + 64 + dd]);
  for (int dd = 0; dd < 64; dd++)
    s += bte[dd] * Wih0[row * 208 + 144 + dd];
  bias0[p] = s;
  bias1[p] = bih1[row] + bhh1[row];
}

__global__ void k_pe(const float* __restrict__ Wih0, const float* __restrict__ bias0,
                     float* __restrict__ peg) {
  int tid = blockIdx.x * 256 + threadIdx.x;   // < 512000
  int t = tid >> 9, p = tid & 511;
  int row = (p & 3) * 128 + (p >> 2);
  float acc = bias0[p];
  float tf = (float)t;
  #pragma unroll
  for (int i = 0; i < 8; i++) {
    float div = expf(-1.1512925464970228f * (float)i);  // exp(2i * -ln(10000)/16)
    float ang = tf * div;
    acc += sinf(ang) * Wih0[row * 208 + 128 + 2 * i]
         + cosf(ang) * Wih0[row * 208 + 129 + 2 * i];
  }
  peg[tid] = acc;
}

// =======================================================================
// pipelined 2-group LSTM: blocks 0..31 layer0 (A), 32..63 layer1 (B)
// ring slot layout (k-major frags): idx = ((k>>3)*16 + m)*8 + (k&7), 2048 halfs
// =======================================================================
__global__ __launch_bounds__(512, 2) void k_lstm5(
    const float* __restrict__ xs, const float* __restrict__ xtc,
    const _Float16* __restrict__ w0s, const _Float16* __restrict__ w1s,
    const float* __restrict__ peg, const float* __restrict__ b1g,
    _Float16* __restrict__ ring, int* cnt, float* __restrict__ h1l) {
  __shared__ __align__(16) _Float16 sm[36992];   // 73984 B
  const int tidx = threadIdx.x, lane = tidx & 63, wv = tidx >> 6;
  const int q = lane >> 4, mcol = lane & 15;
  const f4 z4 = {0.f, 0.f, 0.f, 0.f};

  if (blockIdx.x < 32) {
    // ================= A: layer 0 =================
    const int g = blockIdx.x;
    int* flag = cnt + g * 64;
    int* cons = cnt + 2048 + g * 64;
    _Float16* rg = ring + (size_t)g * 65536;

    for (int i = tidx; i < 16 * SROWA; i += 512) sm[i] = (_Float16)0.f;

    h8 wf0[4][6];
    #pragma unroll
    for (int j = 0; j < 4; j++)
      #pragma unroll
      for (int ks = 0; ks < 6; ks++)
        wf0[j][ks] = ((const h8*)w0s)[((wv * 4 + j) * 6 + ks) * 64 + lane];

    float c0[4] = {0.f, 0.f, 0.f, 0.f};
    h8 h0f[4];
    #pragma unroll
    for (int i = 0; i < 4; i++) h0f[i] = (h8)(_Float16)0.f;

    const bool isA = tidx < 64;
    const int sa_row = tidx >> 2, sa_c = (tidx & 3) * 4;
    const bool isB = (tidx >= 64) && (tidx < 272);
    const int t2 = tidx - 64;
    const int tb_row = t2 / 13, tb_c = (t2 - tb_row * 13) * 2;
    _Float16* arow = sm + sa_row * SROWA;
    _Float16* brow = sm + tb_row * SROWA;
    _Float16* srow = sm + mcol * SROWA;

    h4v xe = {(_Float16)0.f, (_Float16)0.f, (_Float16)0.f, (_Float16)0.f};
    _Float16 te0 = (_Float16)0.f, te1 = (_Float16)0.f;
    if (isA) {
      const float* xb = xs + ((size_t)(g * 16 + sa_row) * 1000 + 0) * 32;
      f4 a = *(const f4*)(xb + sa_c), b = *(const f4*)(xb + 16 + sa_c);
      h4v o = {(_Float16)(a[0] + b[0]), (_Float16)(a[1] + b[1]),
               (_Float16)(a[2] + b[2]), (_Float16)(a[3] + b[3])};
      *(h4v*)(arow + sa_c) = o;
      const float* xb1 = xs + ((size_t)(g * 16 + sa_row) * 1000 + 1) * 32;
      f4 a1v = *(const f4*)(xb1 + sa_c), b1v = *(const f4*)(xb1 + 16 + sa_c);
      xe[0] = (_Float16)(a1v[0] + b1v[0]); xe[1] = (_Float16)(a1v[1] + b1v[1]);
      xe[2] = (_Float16)(a1v[2] + b1v[2]); xe[3] = (_Float16)(a1v[3] + b1v[3]);
    }
    if (isB) {
      float2 tv = *(const float2*)(xtc + ((size_t)(g * 16 + tb_row) * 1000 + 0) * 26 + tb_c);
      brow[16 + tb_c] = (_Float16)tv.x; brow[16 + tb_c + 1] = (_Float16)tv.y;
      float2 tv1 = *(const float2*)(xtc + ((size_t)(g * 16 + tb_row) * 1000 + 1) * 26 + tb_c);
      te0 = (_Float16)tv1.x; te1 = (_Float16)tv1.y;
    }
    __syncthreads();

    #pragma unroll 1
    for (int t = 0; t < 1000; t++) {
      if ((t & 7) == 0 && t >= 32) {     // ring-full guard (B within 24 steps)
        if (tidx == 0) poll_ge(cons, t - 24);
        bar_lds();
      }
      const int tn = (t < 998) ? t + 2 : 999;
      f4 sA = z4, sB = z4; float2 tvr = {0.f, 0.f};
      if (isA) {
        const float* xb = xs + ((size_t)(g * 16 + sa_row) * 1000 + tn) * 32;
        sA = *(const f4*)(xb + sa_c); sB = *(const f4*)(xb + 16 + sa_c);
      }
      if (isB) tvr = *(const float2*)(xtc + ((size_t)(g * 16 + tb_row) * 1000 + tn) * 26 + tb_c);

      f4 acc[4];
      #pragma unroll
      for (int j = 0; j < 4; j++)
        acc[j] = *(const f4*)(peg + (size_t)t * 512 + wv * 64 + q * 16 + j * 4);
      const int xoff = (t & 1) * 64;
      h8 xf0 = *(const h8*)(srow + xoff + q * 8);
      h8 xf1 = *(const h8*)(srow + xoff + 32 + q * 8);
      #pragma unroll
      for (int j = 0; j < 4; j++)
        acc[j] = __builtin_amdgcn_mfma_f32_16x16x32_f16(wf0[j][0], xf0, acc[j], 0, 0, 0);
      #pragma unroll
      for (int j = 0; j < 4; j++)
        acc[j] = __builtin_amdgcn_mfma_f32_16x16x32_f16(wf0[j][1], xf1, acc[j], 0, 0, 0);
      #pragma unroll
      for (int ks = 0; ks < 4; ks++)
        #pragma unroll
        for (int j = 0; j < 4; j++)
          acc[j] = __builtin_amdgcn_mfma_f32_16x16x32_f16(wf0[j][2 + ks], h0f[ks], acc[j], 0, 0, 0);

      h4v hv0;
      #pragma unroll
      for (int j = 0; j < 4; j++) {
        float cc = sigf(acc[j][1]) * c0[j] + sigf(acc[j][0]) * tanhfast(acc[j][2]);
        c0[j] = cc;
        hv0[j] = (_Float16)(sigf(acc[j][3]) * tanhfast(cc));
      }
      *(h4v*)(srow + 128 + (t & 1) * 128 + wv * 16 + q * 4) = hv0;
      // ring publish (k-major frag layout)
      *(h4v*)(rg + (size_t)(t & 31) * 2048 +
              ((size_t)((wv * 2 + (q >> 1)) * 16 + mcol)) * 8 + (q & 1) * 4) = hv0;
      // stage x(t+1) from regs
      if (isA) *(h4v*)(arow + ((t + 1) & 1) * 64 + sa_c) = xe;
      if (isB) {
        brow[((t + 1) & 1) * 64 + 16 + tb_c] = te0;
        brow[((t + 1) & 1) * 64 + 16 + tb_c + 1] = te1;
      }
      // consume prefetched x(t+2)
      if (isA) {
        xe[0] = (_Float16)(sA[0] + sB[0]); xe[1] = (_Float16)(sA[1] + sB[1]);
        xe[2] = (_Float16)(sA[2] + sB[2]); xe[3] = (_Float16)(sA[3] + sB[3]);
      }
      if (isB) { te0 = (_Float16)tvr.x; te1 = (_Float16)tvr.y; }

      if ((t & 7) == 7) {
        __syncthreads();   // drains vmcnt per wave -> all ring stores in L2
        if (tidx == 0) {
          __builtin_amdgcn_fence(__ATOMIC_RELEASE, "agent");  // L2 writeback
          __hip_atomic_store(flag, t + 1, __ATOMIC_RELAXED, __HIP_MEMORY_SCOPE_AGENT);
        }
      } else {
        bar_lds();
      }
      #pragma unroll
      for (int i = 0; i < 4; i++)
        h0f[i] = *(const h8*)(srow + 128 + (t & 1) * 128 + i * 32 + q * 8);
    }
  } else {
    // ================= B: layer 1 =================
    const int g = blockIdx.x - 32;
    int* flag = cnt + g * 64;
    int* cons = cnt + 2048 + g * 64;
    const _Float16* rg = ring + (size_t)g * 65536;

    for (int i = tidx; i < 4224; i += 512) sm[B_H1 + i] = (_Float16)0.f;

    h8 wf1[4][8];
    #pragma unroll
    for (int j = 0; j < 4; j++)
      #pragma unroll
      for (int ks = 0; ks < 8; ks++)
        wf1[j][ks] = ((const h8*)w1s)[((wv * 4 + j) * 8 + ks) * 64 + lane];
    f4 b1r[4];
    #pragma unroll
    for (int j = 0; j < 4; j++)
      b1r[j] = *(const f4*)(b1g + wv * 64 + q * 16 + j * 4);

    float c1[4] = {0.f, 0.f, 0.f, 0.f};
    _Float16* h1row = sm + B_H1 + mcol * 264;
    uint4 cr[4];

    // prologue: chunk 0
    if (tidx == 0) { poll_ge(flag, 8); __builtin_amdgcn_fence(__ATOMIC_ACQUIRE, "agent"); }
    __syncthreads();
    {
      const uint4* src = (const uint4*)rg;
      #pragma unroll
      for (int p = 0; p < 4; p++) cr[p] = src[p * 512 + tidx];
      uint4* dst = (uint4*)sm;
      #pragma unroll
      for (int p = 0; p < 4; p++) dst[p * 512 + tidx] = cr[p];
    }
    #pragma unroll 1
    for (int c = 0; c < 125; c++) {
      if (c < 124 && tidx == 0) {
        poll_ge(flag, 8 * (c + 2));
        __builtin_amdgcn_fence(__ATOMIC_ACQUIRE, "agent");   // inv L1/L2 before chunk c+1 reads
      }
      __syncthreads();   // buf[c&1] stores visible; inv done before any lane's loads
      if (c < 124) {
        const uint4* src = (const uint4*)(rg + (size_t)((8 * (c + 1)) & 31) * 2048);
        #pragma unroll
        for (int p = 0; p < 4; p++) cr[p] = src[p * 512 + tidx];
      }
      _Float16* buf = sm + (c & 1) * 16384;
      #pragma unroll 1
      for (int s = 0; s < 8; s++) {
        const int t = c * 8 + s;
        h8 h0f[4], h1f[4];
        #pragma unroll
        for (int i = 0; i < 4; i++)
          h0f[i] = *(const h8*)(buf + s * 2048 + ((i * 4 + q) * 16 + mcol) * 8);
        #pragma unroll
        for (int i = 0; i < 4; i++)
          h1f[i] = *(const h8*)(h1row + (t & 1) * 128 + i * 32 + q * 8);
        f4 a1[4] = {b1r[0], b1r[1], b1r[2], b1r[3]};
        #pragma unroll
        for (int ks = 0; ks < 4; ks++)
          #pragma unroll
          for (int j = 0; j < 4; j++)
            a1[j] = __builtin_amdgcn_mfma_f32_16x16x32_f16(wf1[j][4 + ks], h1f[ks], a1[j], 0, 0, 0);
        #pragma unroll
        for (int ks = 0; ks < 4; ks++)
          #pragma unroll
          for (int j = 0; j < 4; j++)
            a1[j] = __builtin_amdgcn_mfma_f32_16x16x32_f16(wf1[j][ks], h0f[ks], a1[j], 0, 0, 0);
        h4v hv1; f4 hfv;
        #pragma unroll
        for (int j = 0; j < 4; j++) {
          float cc = sigf(a1[j][1]) * c1[j] + sigf(a1[j][0]) * tanhfast(a1[j][2]);
          c1[j] = cc;
          float h = sigf(a1[j][3]) * tanhfast(cc);
          hfv[j] = h;
          hv1[j] = (_Float16)h;
        }
        *(h4v*)(h1row + ((t + 1) & 1) * 128 + wv * 16 + q * 4) = hv1;
        if (t == 999)
          *(f4*)(h1l + (size_t)(g * 16 + mcol) * 128 + wv * 16 + q * 4) = hfv;
        bar_lds();
      }
      if (c < 124) {
        uint4* dst = (uint4*)(sm + ((c + 1) & 1) * 16384);
        #pragma unroll
        for (int p = 0; p < 4; p++) dst[p * 512 + tidx] = cr[p];
      }
      if (tidx == 0)
        __hip_atomic_store(cons, 8 * (c + 1), __ATOMIC_RELAXED, __HIP_MEMORY_SCOPE_AGENT);
    }
  }
}

// ---- MLP head: one block per batch row ----
__global__ void k_mlp(const float* __restrict__ h1l,
                      const float* __restrict__ W1, const float* __restrict__ b1,
                      const float* __restrict__ W2, const float* __restrict__ b2,
                      const float* __restrict__ W3, const float* __restrict__ b3,
                      float* __restrict__ out) {
  __shared__ float sh[128];
  __shared__ float sy1[128];
  __shared__ float sy2[64];
  const int b = blockIdx.x;
  const int t = threadIdx.x;   // 128 threads
  sh[t] = h1l[b * 128 + t];
  __syncthreads();
  {
    float s = b1[t];
    const float* wr = W1 + t * 128;
    for (int k = 0; k < 128; k++) s += sh[k] * wr[k];
    sy1[t] = fmaxf(s, 0.f);
  }
  __syncthreads();
  if (t < 64) {
    float s = b2[t];
    const float* wr = W2 + t * 128;
    for (int k = 0; k < 128; k++) s += sy1[k] * wr[k];
    sy2[t] = fmaxf(s, 0.f);
  }
  __syncthreads();
  if (t < 26) {
    float s = b3[t];
    const float* wr = W3 + t * 64;
    for (int k = 0; k < 64; k++) s += sy2[k] * wr[k];
    out[b * 26 + t] = s;
  }
}

extern "C" void kernel_launch(void* const* d_in, const int* in_sizes, int n_in,
                              void* d_out, int out_size, void* d_ws, size_t ws_size,
                              hipStream_t stream) {
  const float* xs   = (const float*)d_in[0];
  const float* xtc  = (const float*)d_in[1];
  const float* Wgcn = (const float*)d_in[2];
  const float* bgcn = (const float*)d_in[3];
  const float* Wte  = (const float*)d_in[4];
  const float* bte  = (const float*)d_in[5];
  const float* Wih0 = (const float*)d_in[6];
  const float* Whh0 = (const float*)d_in[7];
  const float* bih0 = (const float*)d_in[8];
  const float* bhh0 = (const float*)d_in[9];
  const float* Wih1 = (const float*)d_in[10];
  const float* Whh1 = (const float*)d_in[11];
  const float* bih1 = (const float*)d_in[12];
  const float* bhh1 = (const float*)d_in[13];
  const float* W1   = (const float*)d_in[14];
  const float* b1   = (const float*)d_in[15];
  const float* W2   = (const float*)d_in[16];
  const float* b2   = (const float*)d_in[17];
  const float* W3   = (const float*)d_in[18];
  const float* b3   = (const float*)d_in[19];

  char* ws = (char*)d_ws;
  if (ws_size < WS_NEED) return;

  _Float16* w0s  = (_Float16*)(ws + O_W0);
  _Float16* w1s  = (_Float16*)(ws + O_W1);
  float* bias0   = (float*)(ws + O_B0);
  float* bias1   = (float*)(ws + O_B1);
  float* peg     = (float*)(ws + O_PE);
  float* h1l     = (float*)(ws + O_H1);
  _Float16* ring = (_Float16*)(ws + O_RING);
  int* cnt       = (int*)(ws + O_CNT);

  hipMemsetAsync(ws + O_CNT, 0, 16384, stream);
  hipLaunchKernelGGL(k_bias, dim3(1), dim3(512), 0, stream, bih0, bhh0, bgcn, bte, Wih0, bih1, bhh1, bias0, bias1);
  hipLaunchKernelGGL(k_pe, dim3(2000), dim3(256), 0, stream, Wih0, bias0, peg);
  hipLaunchKernelGGL(k_wswz0n, dim3(384), dim3(256), 0, stream, Wgcn, Wte, Wih0, Whh0, w0s);
  hipLaunchKernelGGL(k_wswz1n, dim3(512), dim3(256), 0, stream, Wih1, Whh1, w1s);
  hipLaunchKernelGGL(k_lstm5, dim3(64), dim3(512), 0, stream, xs, xtc, w0s, w1s, peg, bias1, ring, cnt, h1l);
  hipLaunchKernelGGL(k_mlp, dim3(512), dim3(128), 0, stream, h1l, W1, b1, W2, b2, W3, b3, (float*)d_out);
}